// Round 1
// baseline (1125.681 us; speedup 1.0000x reference)
//
#include <hip/hip_runtime.h>
#include <hip/hip_bf16.h>

// GraphEMALayer - MI355X (gfx950) - round 14: two-phase bucketed CSR fill.
// R13 counters: ema_fill = 126 us, WRITE_SIZE 105.8 MB for a 6.4 MB csr
// (16x write amplification from random 4B scatters; lines evicted between
// partial writes across XCDs). Replace the one-shot scatter with:
//   bucket pass: edges -> 391 buckets (dst>>8), packed (dst&255)<<24|src,
//     slot = rs[b<<8] + atomicAdd(bcnt[b]) -- 391 sequential write pointers.
//   fillcsr pass: 1 block per bucket; staging segment (~16KB) + csr window
//     are block/XCD-local in L2; per-node slots via LDS counters; full
//     lines written once -> HBM writes ~= 6.4 MB.
// rs now stays as segment STARTS (no atomic mutation); passes A-D use
// j = rs[wid], end = j + deg. Staging aliases W1m1 (dead until pass A);
// bcnt reuses bsum (re-zeroed in ema_coef, which runs after scan3).
// Everything else (closed-form per-pass expansion, bf16 shadows) unchanged.

static __device__ __forceinline__ float bf2f(unsigned short v) {
    union { unsigned int u; float f; } x;
    x.u = ((unsigned int)v) << 16;
    return x.f;
}

static __device__ __forceinline__ unsigned short f2bf(float f) {
    union { unsigned int u; float f; } x;
    x.f = f;
    unsigned int r = x.u + 0x7FFFu + ((x.u >> 16) & 1u);
    return (unsigned short)(r >> 16);
}

__global__ void ema_zero_kernel(int* degi) {
    int i = (int)(blockIdx.x * 256 + threadIdx.x);
    if (i < 100000) degi[i] = 0;
}

// h = x@W + b -> bf16 shadow only (own-row h is read back as bf16).
__global__ void ema_gemm_kernel(const float* x, const float* W,
                                const float* bias, unsigned short* hbf) {
    int i = (int)(blockIdx.x * 256 + threadIdx.x);
    if (i >= 100000 * 64) return;
    int v = i >> 6;
    int c = i & 63;
    float acc = bias[c];
    const float* xr = x + v * 64;
    for (int k = 0; k < 64; ++k) {
        acc = fmaf(xr[k], W[k * 64 + c], acc);
    }
    hbf[i] = f2bf(acc);
}

__global__ void ema_degcount_kernel(const int* ei, int* degi) {
    int e = (int)(blockIdx.x * 256 + threadIdx.x);
    if (e < 1600000) atomicAdd(&degi[ei[e]], 1);
}

__global__ void ema_scan1_kernel(const int* degi, int* bsum) {
    __shared__ int s[256];
    int i = (int)(blockIdx.x * 256 + threadIdx.x);
    int t = (int)threadIdx.x;
    s[t] = (i < 100000) ? degi[i] : 0;
    __syncthreads();
    for (int off = 128; off > 0; off >>= 1) {
        if (t < off) s[t] += s[t + off];
        __syncthreads();
    }
    if (t == 0) bsum[blockIdx.x] = s[0];
}

__global__ void ema_scan2_kernel(int* bsum) {
    __shared__ int s[512];
    int t = (int)threadIdx.x;
    int v = (t < 391) ? bsum[t] : 0;
    s[t] = v;
    __syncthreads();
    for (int off = 1; off < 512; off <<= 1) {
        int add = (t >= off) ? s[t - off] : 0;
        __syncthreads();
        s[t] += add;
        __syncthreads();
    }
    if (t < 391) bsum[t] = s[t] - v;
}

__global__ void ema_scan3_kernel(const int* degi, const int* bsum, int* rs) {
    __shared__ int s[256];
    int i = (int)(blockIdx.x * 256 + threadIdx.x);
    int t = (int)threadIdx.x;
    int v = (i < 100000) ? degi[i] : 0;
    s[t] = v;
    __syncthreads();
    for (int off = 1; off < 256; off <<= 1) {
        int add = (t >= off) ? s[t - off] : 0;
        __syncthreads();
        s[t] += add;
        __syncthreads();
    }
    if (i < 100000) rs[i] = bsum[blockIdx.x] + s[t] - v;
}

// Per-node (alpha, c): leaf -> (1, 0); else (0.5, 0.5/(deg-1+eps)).
// Also re-zeroes bcnt (aliases bsum; scan3 already consumed it).
__global__ void ema_coef_kernel(const int* degi, float2* coef, int* bcnt) {
    int v = (int)(blockIdx.x * 256 + threadIdx.x);
    if (v < 391) bcnt[v] = 0;
    if (v >= 100000) return;
    int d = degi[v];
    float2 q;
    if (d <= 1) {
        q.x = 1.0f;
        q.y = 0.0f;
    } else {
        q.x = 0.5f;
        q.y = 0.5f / ((float)d - 1.0f + 1e-9f);
    }
    coef[v] = q;
}

// Bucket pass: each edge -> bucket (dst>>8); staging slot within the
// bucket's exact csr segment [rs[b<<8], rs[b<<8]+bucket_size).
// Packed entry: (dst&255)<<24 | src  (src < 2^17).
__global__ void ema_bucket_kernel(const int* ei, const int* rs, int* bcnt,
                                  unsigned int* stage) {
    int e = (int)(blockIdx.x * 256 + threadIdx.x);
    if (e >= 1600000) return;
    int src = ei[e];
    int dst = (e < 800000) ? ei[e + 800000] : ei[e - 800000];
    int b = dst >> 8;
    int slot = rs[b << 8] + atomicAdd(&bcnt[b], 1);
    stage[slot] = ((unsigned int)(dst & 255) << 24) | (unsigned int)src;
}

// CSR pass: one block per bucket. Staging segment + csr window are
// XCD-local (~16 KB each); per-node slots via LDS counters.
__global__ void ema_fillcsr_kernel(const int* rs, const unsigned int* stage,
                                   int* csr) {
    __shared__ int rsl[256];
    __shared__ int cnt[256];
    int b = (int)blockIdx.x;
    int t = (int)threadIdx.x;
    int node_lo = b << 8;
    int node = node_lo + t;
    rsl[t] = (node < 100000) ? rs[node] : 1600000;
    cnt[t] = 0;
    __syncthreads();
    int seg_lo = rsl[0];
    int seg_hi = (node_lo + 256 < 100000) ? rs[node_lo + 256] : 1600000;
    for (int i = seg_lo + t; i < seg_hi; i += 256) {
        unsigned int v = stage[i];
        int local = (int)(v >> 24);
        int srcn = (int)(v & 0x00FFFFFFu);
        int slot = rsl[local] + atomicAdd(&cnt[local], 1);
        csr[slot] = srcn;
    }
}

// Pass A: gather hbf rows; emit m0, W1, W2, W3a and pp=(r c P1, r c).
__global__ void ema_passA_kernel(const int* degi, const int* rs, const int* csr,
                                 const float2* coef, const unsigned short* hbf,
                                 unsigned short* m0, unsigned short* W1,
                                 unsigned short* W2, unsigned short* W3a,
                                 float2* pp) {
    int wid = (int)((blockIdx.x * 256 + threadIdx.x) >> 6);
    int c = (int)(threadIdx.x & 63);
    if (wid >= 100000) return;
    int dv = degi[wid];
    int base = wid * 64 + c;
    float hv = bf2f(hbf[base]);
    if (dv == 0) {
        m0[base] = 0;
        W1[base] = 0;
        W2[base] = 0;
        W3a[base] = f2bf(hv);   // y = h for isolated nodes
        if (c == 0) pp[wid] = make_float2(0.0f, 0.0f);
        return;
    }
    int j = rs[wid];
    int end = j + dv;
    float2 qv = coef[wid];
    float fv = qv.x * hv;
    float cv = qv.y;
    float sm = 0.0f, sS = 0.0f, sQ = 0.0f, p1 = 0.0f, p2 = 0.0f;
    for (; j + 4 <= end; j += 4) {
        int a0 = csr[j], a1 = csr[j + 1], a2 = csr[j + 2], a3 = csr[j + 3];
        float2 q0 = coef[a0], q1 = coef[a1], q2 = coef[a2], q3 = coef[a3];
        float h0 = bf2f(hbf[a0 * 64 + c]);
        float h1 = bf2f(hbf[a1 * 64 + c]);
        float h2 = bf2f(hbf[a2 * 64 + c]);
        float h3 = bf2f(hbf[a3 * 64 + c]);
        sm += (h0 + h1) + (h2 + h3);
        sS += q0.x * h0 + q1.x * h1 + q2.x * h2 + q3.x * h3;
        sQ += q0.y * h0 + q1.y * h1 + q2.y * h2 + q3.y * h3;
        p1 += (q0.y + q1.y) + (q2.y + q3.y);
        p2 += q0.y * q0.y + q1.y * q1.y + q2.y * q2.y + q3.y * q3.y;
    }
    for (; j < end; ++j) {
        int a = csr[j];
        float2 qa = coef[a];
        float ha = bf2f(hbf[a * 64 + c]);
        sm += ha;
        sS += qa.x * ha;
        sQ += qa.y * ha;
        p1 += qa.y;
        p2 += qa.y * qa.y;
    }
    float r = 0.5f / ((float)dv + 1e-9f);
    float w1 = sS - hv * p1;
    float w2 = sS - fv * p1 - cv * p1 * sm + cv * sQ;
    float w3 = 0.5f * hv + r * (sS - fv * p1 + 0.5f * cv * sQ - cv * hv * p2);
    m0[base] = f2bf(sm);
    W1[base] = f2bf(w1);
    W2[base] = f2bf(w2);
    W3a[base] = f2bf(w3);
    if (c == 0) pp[wid] = make_float2(r * cv * p1, r * cv);
}

// Pass B: gather m0 rows; m1 = W1 + sum c_a m0[a] (in place over W1);
// W4 = W3a - pp.x*m1 + pp.y*U, U = sum c_a^2 m0[a] (in place over W3a).
__global__ void ema_passB_kernel(const int* degi, const int* rs, const int* csr,
                                 const float2* coef, const unsigned short* m0,
                                 unsigned short* W1m1, unsigned short* W3W4,
                                 const float2* pp) {
    int wid = (int)((blockIdx.x * 256 + threadIdx.x) >> 6);
    int c = (int)(threadIdx.x & 63);
    if (wid >= 100000) return;
    int dv = degi[wid];
    if (dv == 0) return;   // slots already hold m1=0, W4=h from pass A
    int base = wid * 64 + c;
    int j = rs[wid];
    int end = j + dv;
    float t1 = 0.0f, t2 = 0.0f;
    for (; j + 4 <= end; j += 4) {
        int a0 = csr[j], a1 = csr[j + 1], a2 = csr[j + 2], a3 = csr[j + 3];
        float c0 = coef[a0].y, c1 = coef[a1].y, c2 = coef[a2].y, c3 = coef[a3].y;
        float m0v = bf2f(m0[a0 * 64 + c]);
        float m1v = bf2f(m0[a1 * 64 + c]);
        float m2v = bf2f(m0[a2 * 64 + c]);
        float m3v = bf2f(m0[a3 * 64 + c]);
        t1 += c0 * m0v + c1 * m1v + c2 * m2v + c3 * m3v;
        t2 += c0 * c0 * m0v + c1 * c1 * m1v + c2 * c2 * m2v + c3 * c3 * m3v;
    }
    for (; j < end; ++j) {
        int a = csr[j];
        float ca = coef[a].y;
        float mv = bf2f(m0[a * 64 + c]);
        t1 += ca * mv;
        t2 += ca * ca * mv;
    }
    float2 ppv = pp[wid];
    float m1 = bf2f(W1m1[base]) + t1;
    float w4 = bf2f(W3W4[base]) - ppv.x * m1 + ppv.y * t2;
    W1m1[base] = f2bf(m1);
    W3W4[base] = f2bf(w4);
}

// Pass C: gather m1 rows; m2 = W2 + sum c_a m1[a] (in place over W2).
__global__ void ema_passC_kernel(const int* degi, const int* rs, const int* csr,
                                 const float2* coef, const unsigned short* m1,
                                 unsigned short* W2m2) {
    int wid = (int)((blockIdx.x * 256 + threadIdx.x) >> 6);
    int c = (int)(threadIdx.x & 63);
    if (wid >= 100000) return;
    int dv = degi[wid];
    if (dv == 0) return;   // slot already holds m2=0
    int base = wid * 64 + c;
    int j = rs[wid];
    int end = j + dv;
    float t = 0.0f;
    for (; j + 4 <= end; j += 4) {
        int a0 = csr[j], a1 = csr[j + 1], a2 = csr[j + 2], a3 = csr[j + 3];
        float c0 = coef[a0].y, c1 = coef[a1].y, c2 = coef[a2].y, c3 = coef[a3].y;
        float m0v = bf2f(m1[a0 * 64 + c]);
        float m1v = bf2f(m1[a1 * 64 + c]);
        float m2v = bf2f(m1[a2 * 64 + c]);
        float m3v = bf2f(m1[a3 * 64 + c]);
        t += c0 * m0v + c1 * m1v + c2 * m2v + c3 * m3v;
    }
    for (; j < end; ++j) {
        int a = csr[j];
        t += coef[a].y * bf2f(m1[a * 64 + c]);
    }
    float m2v = bf2f(W2m2[base]) + t;
    W2m2[base] = f2bf(m2v);
}

// Pass D (identifier kernel): gather m2 rows; y = W4 + r*sum c_a m2[a];
// out = x + relu(y). Overwrites all of d_out (m0 region is dead).
__global__ void GraphEMALayer_18133351924067_kernel(
    const int* degi, const int* rs, const int* csr, const float2* coef,
    const unsigned short* m2, const unsigned short* W4,
    const float* x, float* out) {
    int wid = (int)((blockIdx.x * 256 + threadIdx.x) >> 6);
    int c = (int)(threadIdx.x & 63);
    if (wid >= 100000) return;
    int dv = degi[wid];
    int base = wid * 64 + c;
    float xv = x[base];
    float y = bf2f(W4[base]);
    if (dv > 0) {
        int j = rs[wid];
        int end = j + dv;
        float t = 0.0f;
        for (; j + 4 <= end; j += 4) {
            int a0 = csr[j], a1 = csr[j + 1], a2 = csr[j + 2], a3 = csr[j + 3];
            float c0 = coef[a0].y, c1 = coef[a1].y, c2 = coef[a2].y, c3 = coef[a3].y;
            float m0v = bf2f(m2[a0 * 64 + c]);
            float m1v = bf2f(m2[a1 * 64 + c]);
            float m2v = bf2f(m2[a2 * 64 + c]);
            float m3v = bf2f(m2[a3 * 64 + c]);
            t += c0 * m0v + c1 * m1v + c2 * m2v + c3 * m3v;
        }
        for (; j < end; ++j) {
            int a = csr[j];
            t += coef[a].y * bf2f(m2[a * 64 + c]);
        }
        float r = 0.5f / ((float)dv + 1e-9f);
        y += r * t;
    }
    if (y < 0.0f) y = 0.0f;
    out[base] = xv + y;
}

extern "C" void kernel_launch(void* const* d_in, const int* in_sizes, int n_in,
                              void* d_out, int out_size, void* d_ws, size_t ws_size,
                              hipStream_t stream) {
    (void)in_sizes; (void)n_in; (void)out_size; (void)ws_size;

    const float* x    = (const float*)d_in[0];
    const int*   ei   = (const int*)d_in[1];
    const float* W    = (const float*)d_in[2];
    const float* bias = (const float*)d_in[3];
    float* out = (float*)d_out;
    unsigned short* m0 = (unsigned short*)d_out;   // first 12.8 MB, dead before D

    char* ws = (char*)d_ws;
    unsigned short* hbf  = (unsigned short*)(ws);             // 12,800,000 B
    unsigned short* W1m1 = (unsigned short*)(ws + 12800000);  // 12,800,000 B
    unsigned short* W2m2 = (unsigned short*)(ws + 25600000);  // 12,800,000 B
    unsigned short* W3W4 = (unsigned short*)(ws + 38400000);  // 12,800,000 B
    int* degi = (int*)(ws + 51200000);                        //    400,000 B
    int* rs   = (int*)(ws + 51600000);                        //    400,000 B
    float2* coef = (float2*)(ws + 52000000);                  //    800,000 B
    float2* pp   = (float2*)(ws + 52800000);                  //    800,000 B
    int* csr  = (int*)(ws + 53600000);                        //  6,400,000 B
    int* bsum = (int*)(ws + 60000000);                        //      4,096 B

    // Staging for the bucket pass aliases W1m1 (dead until pass A).
    unsigned int* stage = (unsigned int*)(ws + 12800000);     //  6,400,000 B
    int* bcnt = bsum;   // reused after scan3; zeroed in ema_coef_kernel

    int eb = (100000 * 64 + 255) / 256;   // 25000 blocks: wave-per-node grids
    int nb = (100000 + 255) / 256;        //   391 blocks: per-node grids
    int db = (1600000 + 255) / 256;       //  6250 blocks: per-edge grids

    ema_zero_kernel<<<nb, 256, 0, stream>>>(degi);
    ema_gemm_kernel<<<eb, 256, 0, stream>>>(x, W, bias, hbf);
    ema_degcount_kernel<<<db, 256, 0, stream>>>(ei, degi);

    ema_scan1_kernel<<<nb, 256, 0, stream>>>(degi, bsum);
    ema_scan2_kernel<<<1, 512, 0, stream>>>(bsum);
    ema_scan3_kernel<<<nb, 256, 0, stream>>>(degi, bsum, rs);
    ema_coef_kernel<<<nb, 256, 0, stream>>>(degi, coef, bcnt);

    ema_bucket_kernel<<<db, 256, 0, stream>>>(ei, rs, bcnt, stage);
    ema_fillcsr_kernel<<<nb, 256, 0, stream>>>(rs, stage, csr);

    ema_passA_kernel<<<eb, 256, 0, stream>>>(degi, rs, csr, coef, hbf,
                                             m0, W1m1, W2m2, W3W4, pp);
    ema_passB_kernel<<<eb, 256, 0, stream>>>(degi, rs, csr, coef, m0,
                                             W1m1, W3W4, pp);
    ema_passC_kernel<<<eb, 256, 0, stream>>>(degi, rs, csr, coef, W1m1, W2m2);
    GraphEMALayer_18133351924067_kernel<<<eb, 256, 0, stream>>>(
        degi, rs, csr, coef, W2m2, W3W4, x, out);
}

// Round 2
// 590.773 us; speedup vs baseline: 1.9054x; 1.9054x over previous
//
#include <hip/hip_runtime.h>
#include <hip/hip_bf16.h>

// GraphEMALayer - MI355X (gfx950) - round 15: contention-free bucketed fill.
// R14 post-mortem: ema_bucket = 556 us at 1.6% HBM / 0.2% VALU -- pure
// global-atomic serialization (1.6M atomicAdds on 391 bcnt addresses =
// ~4090 serialized RMWs/address @ ~136 ns each). Fix: deterministic
// 3-step partition with NO contended global atomics:
//   ema_hist:   391 blocks x 4096 edges; LDS histogram over 391 buckets;
//               write hcnt[bucket][block] (611 KB, aliases dead W2m2).
//   ema_bscan:  1 block/bucket; exclusive scan of its 391 block-counts
//               + rs[bucket<<8] -> per-(bucket,block) base. Zero atomics.
//   ema_scatter:re-read edges (L2-hot); slot = base[bu]+LDS-cnt; packed
//               (dst&255)<<24|src into stage. ~10-entry contiguous runs
//               per (block,bucket) -> ~1.6x write amp (~10 MB, was 63).
//   ema_fillcsr: unchanged from R14 (1 block/bucket, LDS per-node slots,
//               full-line csr writes -- this phase was never the problem).
// rs stays segment STARTS; passes A-D use j=rs[wid], end=j+deg.
// Closed-form per-pass expansion (R13) unchanged. Workspace 60.0 MB.

static __device__ __forceinline__ float bf2f(unsigned short v) {
    union { unsigned int u; float f; } x;
    x.u = ((unsigned int)v) << 16;
    return x.f;
}

static __device__ __forceinline__ unsigned short f2bf(float f) {
    union { unsigned int u; float f; } x;
    x.f = f;
    unsigned int r = x.u + 0x7FFFu + ((x.u >> 16) & 1u);
    return (unsigned short)(r >> 16);
}

__global__ void ema_zero_kernel(int* degi) {
    int i = (int)(blockIdx.x * 256 + threadIdx.x);
    if (i < 100000) degi[i] = 0;
}

// h = x@W + b -> bf16 shadow only (own-row h is read back as bf16).
__global__ void ema_gemm_kernel(const float* x, const float* W,
                                const float* bias, unsigned short* hbf) {
    int i = (int)(blockIdx.x * 256 + threadIdx.x);
    if (i >= 100000 * 64) return;
    int v = i >> 6;
    int c = i & 63;
    float acc = bias[c];
    const float* xr = x + v * 64;
    for (int k = 0; k < 64; ++k) {
        acc = fmaf(xr[k], W[k * 64 + c], acc);
    }
    hbf[i] = f2bf(acc);
}

__global__ void ema_degcount_kernel(const int* ei, int* degi) {
    int e = (int)(blockIdx.x * 256 + threadIdx.x);
    if (e < 1600000) atomicAdd(&degi[ei[e]], 1);
}

__global__ void ema_scan1_kernel(const int* degi, int* bsum) {
    __shared__ int s[256];
    int i = (int)(blockIdx.x * 256 + threadIdx.x);
    int t = (int)threadIdx.x;
    s[t] = (i < 100000) ? degi[i] : 0;
    __syncthreads();
    for (int off = 128; off > 0; off >>= 1) {
        if (t < off) s[t] += s[t + off];
        __syncthreads();
    }
    if (t == 0) bsum[blockIdx.x] = s[0];
}

__global__ void ema_scan2_kernel(int* bsum) {
    __shared__ int s[512];
    int t = (int)threadIdx.x;
    int v = (t < 391) ? bsum[t] : 0;
    s[t] = v;
    __syncthreads();
    for (int off = 1; off < 512; off <<= 1) {
        int add = (t >= off) ? s[t - off] : 0;
        __syncthreads();
        s[t] += add;
        __syncthreads();
    }
    if (t < 391) bsum[t] = s[t] - v;
}

__global__ void ema_scan3_kernel(const int* degi, const int* bsum, int* rs) {
    __shared__ int s[256];
    int i = (int)(blockIdx.x * 256 + threadIdx.x);
    int t = (int)threadIdx.x;
    int v = (i < 100000) ? degi[i] : 0;
    s[t] = v;
    __syncthreads();
    for (int off = 1; off < 256; off <<= 1) {
        int add = (t >= off) ? s[t - off] : 0;
        __syncthreads();
        s[t] += add;
        __syncthreads();
    }
    if (i < 100000) rs[i] = bsum[blockIdx.x] + s[t] - v;
}

// Per-node (alpha, c): leaf -> (1, 0); else (0.5, 0.5/(deg-1+eps)).
__global__ void ema_coef_kernel(const int* degi, float2* coef) {
    int v = (int)(blockIdx.x * 256 + threadIdx.x);
    if (v >= 100000) return;
    int d = degi[v];
    float2 q;
    if (d <= 1) {
        q.x = 1.0f;
        q.y = 0.0f;
    } else {
        q.x = 0.5f;
        q.y = 0.5f / ((float)d - 1.0f + 1e-9f);
    }
    coef[v] = q;
}

// Step 1: per-block bucket histogram. Block bl owns edges
// [bl*4096, bl*4096+4096); LDS atomics only; hcnt[bucket*391 + bl].
__global__ void ema_hist_kernel(const int* ei, int* hcnt) {
    __shared__ int hist[391];
    int t = (int)threadIdx.x;
    int bl = (int)blockIdx.x;
    for (int i = t; i < 391; i += 256) hist[i] = 0;
    __syncthreads();
    int e0 = bl * 4096;
    #pragma unroll
    for (int i = 0; i < 16; ++i) {
        int e = e0 + t + i * 256;
        if (e < 1600000) {
            int dst = (e < 800000) ? ei[e + 800000] : ei[e - 800000];
            atomicAdd(&hist[dst >> 8], 1);
        }
    }
    __syncthreads();
    for (int i = t; i < 391; i += 256) hcnt[i * 391 + bl] = hist[i];
}

// Step 2: one block per bucket; exclusive scan of the 391 block counts,
// rebased at the bucket's csr segment start rs[bucket<<8]. No atomics.
__global__ void ema_bscan_kernel(int* hcnt, const int* rs) {
    __shared__ int s[512];
    int bu = (int)blockIdx.x;
    int t = (int)threadIdx.x;
    int v = (t < 391) ? hcnt[bu * 391 + t] : 0;
    s[t] = v;
    __syncthreads();
    for (int off = 1; off < 512; off <<= 1) {
        int add = (t >= off) ? s[t - off] : 0;
        __syncthreads();
        s[t] += add;
        __syncthreads();
    }
    if (t < 391) hcnt[bu * 391 + t] = rs[bu << 8] + s[t] - v;
}

// Step 3: scatter into stage at precomputed per-(bucket,block) bases.
// Re-reads the block's edges (L2-hot); LDS counters give within-run rank.
__global__ void ema_scatter_kernel(const int* ei, const int* hcnt,
                                   unsigned int* stage) {
    __shared__ int base[391];
    __shared__ int cnt[391];
    int t = (int)threadIdx.x;
    int bl = (int)blockIdx.x;
    for (int i = t; i < 391; i += 256) {
        base[i] = hcnt[i * 391 + bl];
        cnt[i] = 0;
    }
    __syncthreads();
    int e0 = bl * 4096;
    #pragma unroll
    for (int i = 0; i < 16; ++i) {
        int e = e0 + t + i * 256;
        if (e < 1600000) {
            int src = ei[e];
            int dst = (e < 800000) ? ei[e + 800000] : ei[e - 800000];
            int bu = dst >> 8;
            int slot = base[bu] + atomicAdd(&cnt[bu], 1);
            stage[slot] = ((unsigned int)(dst & 255) << 24) | (unsigned int)src;
        }
    }
}

// Step 4: one block per bucket. Staging segment + csr window are
// XCD-local (~16 KB each); per-node slots via LDS counters.
__global__ void ema_fillcsr_kernel(const int* rs, const unsigned int* stage,
                                   int* csr) {
    __shared__ int rsl[256];
    __shared__ int cnt[256];
    int b = (int)blockIdx.x;
    int t = (int)threadIdx.x;
    int node_lo = b << 8;
    int node = node_lo + t;
    rsl[t] = (node < 100000) ? rs[node] : 1600000;
    cnt[t] = 0;
    __syncthreads();
    int seg_lo = rsl[0];
    int seg_hi = (node_lo + 256 < 100000) ? rs[node_lo + 256] : 1600000;
    for (int i = seg_lo + t; i < seg_hi; i += 256) {
        unsigned int v = stage[i];
        int local = (int)(v >> 24);
        int srcn = (int)(v & 0x00FFFFFFu);
        int slot = rsl[local] + atomicAdd(&cnt[local], 1);
        csr[slot] = srcn;
    }
}

// Pass A: gather hbf rows; emit m0, W1, W2, W3a and pp=(r c P1, r c).
__global__ void ema_passA_kernel(const int* degi, const int* rs, const int* csr,
                                 const float2* coef, const unsigned short* hbf,
                                 unsigned short* m0, unsigned short* W1,
                                 unsigned short* W2, unsigned short* W3a,
                                 float2* pp) {
    int wid = (int)((blockIdx.x * 256 + threadIdx.x) >> 6);
    int c = (int)(threadIdx.x & 63);
    if (wid >= 100000) return;
    int dv = degi[wid];
    int base = wid * 64 + c;
    float hv = bf2f(hbf[base]);
    if (dv == 0) {
        m0[base] = 0;
        W1[base] = 0;
        W2[base] = 0;
        W3a[base] = f2bf(hv);   // y = h for isolated nodes
        if (c == 0) pp[wid] = make_float2(0.0f, 0.0f);
        return;
    }
    int j = rs[wid];
    int end = j + dv;
    float2 qv = coef[wid];
    float fv = qv.x * hv;
    float cv = qv.y;
    float sm = 0.0f, sS = 0.0f, sQ = 0.0f, p1 = 0.0f, p2 = 0.0f;
    for (; j + 4 <= end; j += 4) {
        int a0 = csr[j], a1 = csr[j + 1], a2 = csr[j + 2], a3 = csr[j + 3];
        float2 q0 = coef[a0], q1 = coef[a1], q2 = coef[a2], q3 = coef[a3];
        float h0 = bf2f(hbf[a0 * 64 + c]);
        float h1 = bf2f(hbf[a1 * 64 + c]);
        float h2 = bf2f(hbf[a2 * 64 + c]);
        float h3 = bf2f(hbf[a3 * 64 + c]);
        sm += (h0 + h1) + (h2 + h3);
        sS += q0.x * h0 + q1.x * h1 + q2.x * h2 + q3.x * h3;
        sQ += q0.y * h0 + q1.y * h1 + q2.y * h2 + q3.y * h3;
        p1 += (q0.y + q1.y) + (q2.y + q3.y);
        p2 += q0.y * q0.y + q1.y * q1.y + q2.y * q2.y + q3.y * q3.y;
    }
    for (; j < end; ++j) {
        int a = csr[j];
        float2 qa = coef[a];
        float ha = bf2f(hbf[a * 64 + c]);
        sm += ha;
        sS += qa.x * ha;
        sQ += qa.y * ha;
        p1 += qa.y;
        p2 += qa.y * qa.y;
    }
    float r = 0.5f / ((float)dv + 1e-9f);
    float w1 = sS - hv * p1;
    float w2 = sS - fv * p1 - cv * p1 * sm + cv * sQ;
    float w3 = 0.5f * hv + r * (sS - fv * p1 + 0.5f * cv * sQ - cv * hv * p2);
    m0[base] = f2bf(sm);
    W1[base] = f2bf(w1);
    W2[base] = f2bf(w2);
    W3a[base] = f2bf(w3);
    if (c == 0) pp[wid] = make_float2(r * cv * p1, r * cv);
}

// Pass B: gather m0 rows; m1 = W1 + sum c_a m0[a] (in place over W1);
// W4 = W3a - pp.x*m1 + pp.y*U, U = sum c_a^2 m0[a] (in place over W3a).
__global__ void ema_passB_kernel(const int* degi, const int* rs, const int* csr,
                                 const float2* coef, const unsigned short* m0,
                                 unsigned short* W1m1, unsigned short* W3W4,
                                 const float2* pp) {
    int wid = (int)((blockIdx.x * 256 + threadIdx.x) >> 6);
    int c = (int)(threadIdx.x & 63);
    if (wid >= 100000) return;
    int dv = degi[wid];
    if (dv == 0) return;   // slots already hold m1=0, W4=h from pass A
    int base = wid * 64 + c;
    int j = rs[wid];
    int end = j + dv;
    float t1 = 0.0f, t2 = 0.0f;
    for (; j + 4 <= end; j += 4) {
        int a0 = csr[j], a1 = csr[j + 1], a2 = csr[j + 2], a3 = csr[j + 3];
        float c0 = coef[a0].y, c1 = coef[a1].y, c2 = coef[a2].y, c3 = coef[a3].y;
        float m0v = bf2f(m0[a0 * 64 + c]);
        float m1v = bf2f(m0[a1 * 64 + c]);
        float m2v = bf2f(m0[a2 * 64 + c]);
        float m3v = bf2f(m0[a3 * 64 + c]);
        t1 += c0 * m0v + c1 * m1v + c2 * m2v + c3 * m3v;
        t2 += c0 * c0 * m0v + c1 * c1 * m1v + c2 * c2 * m2v + c3 * c3 * m3v;
    }
    for (; j < end; ++j) {
        int a = csr[j];
        float ca = coef[a].y;
        float mv = bf2f(m0[a * 64 + c]);
        t1 += ca * mv;
        t2 += ca * ca * mv;
    }
    float2 ppv = pp[wid];
    float m1 = bf2f(W1m1[base]) + t1;
    float w4 = bf2f(W3W4[base]) - ppv.x * m1 + ppv.y * t2;
    W1m1[base] = f2bf(m1);
    W3W4[base] = f2bf(w4);
}

// Pass C: gather m1 rows; m2 = W2 + sum c_a m1[a] (in place over W2).
__global__ void ema_passC_kernel(const int* degi, const int* rs, const int* csr,
                                 const float2* coef, const unsigned short* m1,
                                 unsigned short* W2m2) {
    int wid = (int)((blockIdx.x * 256 + threadIdx.x) >> 6);
    int c = (int)(threadIdx.x & 63);
    if (wid >= 100000) return;
    int dv = degi[wid];
    if (dv == 0) return;   // slot already holds m2=0
    int base = wid * 64 + c;
    int j = rs[wid];
    int end = j + dv;
    float t = 0.0f;
    for (; j + 4 <= end; j += 4) {
        int a0 = csr[j], a1 = csr[j + 1], a2 = csr[j + 2], a3 = csr[j + 3];
        float c0 = coef[a0].y, c1 = coef[a1].y, c2 = coef[a2].y, c3 = coef[a3].y;
        float m0v = bf2f(m1[a0 * 64 + c]);
        float m1v = bf2f(m1[a1 * 64 + c]);
        float m2v = bf2f(m1[a2 * 64 + c]);
        float m3v = bf2f(m1[a3 * 64 + c]);
        t += c0 * m0v + c1 * m1v + c2 * m2v + c3 * m3v;
    }
    for (; j < end; ++j) {
        int a = csr[j];
        t += coef[a].y * bf2f(m1[a * 64 + c]);
    }
    float m2v = bf2f(W2m2[base]) + t;
    W2m2[base] = f2bf(m2v);
}

// Pass D (identifier kernel): gather m2 rows; y = W4 + r*sum c_a m2[a];
// out = x + relu(y). Overwrites all of d_out (m0 region is dead).
__global__ void GraphEMALayer_18133351924067_kernel(
    const int* degi, const int* rs, const int* csr, const float2* coef,
    const unsigned short* m2, const unsigned short* W4,
    const float* x, float* out) {
    int wid = (int)((blockIdx.x * 256 + threadIdx.x) >> 6);
    int c = (int)(threadIdx.x & 63);
    if (wid >= 100000) return;
    int dv = degi[wid];
    int base = wid * 64 + c;
    float xv = x[base];
    float y = bf2f(W4[base]);
    if (dv > 0) {
        int j = rs[wid];
        int end = j + dv;
        float t = 0.0f;
        for (; j + 4 <= end; j += 4) {
            int a0 = csr[j], a1 = csr[j + 1], a2 = csr[j + 2], a3 = csr[j + 3];
            float c0 = coef[a0].y, c1 = coef[a1].y, c2 = coef[a2].y, c3 = coef[a3].y;
            float m0v = bf2f(m2[a0 * 64 + c]);
            float m1v = bf2f(m2[a1 * 64 + c]);
            float m2v = bf2f(m2[a2 * 64 + c]);
            float m3v = bf2f(m2[a3 * 64 + c]);
            t += c0 * m0v + c1 * m1v + c2 * m2v + c3 * m3v;
        }
        for (; j < end; ++j) {
            int a = csr[j];
            t += coef[a].y * bf2f(m2[a * 64 + c]);
        }
        float r = 0.5f / ((float)dv + 1e-9f);
        y += r * t;
    }
    if (y < 0.0f) y = 0.0f;
    out[base] = xv + y;
}

extern "C" void kernel_launch(void* const* d_in, const int* in_sizes, int n_in,
                              void* d_out, int out_size, void* d_ws, size_t ws_size,
                              hipStream_t stream) {
    (void)in_sizes; (void)n_in; (void)out_size; (void)ws_size;

    const float* x    = (const float*)d_in[0];
    const int*   ei   = (const int*)d_in[1];
    const float* W    = (const float*)d_in[2];
    const float* bias = (const float*)d_in[3];
    float* out = (float*)d_out;
    unsigned short* m0 = (unsigned short*)d_out;   // first 12.8 MB, dead before D

    char* ws = (char*)d_ws;
    unsigned short* hbf  = (unsigned short*)(ws);             // 12,800,000 B
    unsigned short* W1m1 = (unsigned short*)(ws + 12800000);  // 12,800,000 B
    unsigned short* W2m2 = (unsigned short*)(ws + 25600000);  // 12,800,000 B
    unsigned short* W3W4 = (unsigned short*)(ws + 38400000);  // 12,800,000 B
    int* degi = (int*)(ws + 51200000);                        //    400,000 B
    int* rs   = (int*)(ws + 51600000);                        //    400,000 B
    float2* coef = (float2*)(ws + 52000000);                  //    800,000 B
    float2* pp   = (float2*)(ws + 52800000);                  //    800,000 B
    int* csr  = (int*)(ws + 53600000);                        //  6,400,000 B
    int* bsum = (int*)(ws + 60000000);                        //      4,096 B

    // CSR-build scratch, both dead before pass A writes them:
    unsigned int* stage = (unsigned int*)(ws + 12800000);     // aliases W1m1, 6.4 MB
    int* hcnt = (int*)(ws + 25600000);                        // aliases W2m2, 611,524 B

    int eb = (100000 * 64 + 255) / 256;   // 25000 blocks: wave-per-node grids
    int nb = (100000 + 255) / 256;        //   391 blocks: per-node grids
    int db = (1600000 + 255) / 256;       //  6250 blocks: per-edge grids
    int pb = (1600000 + 4095) / 4096;     //   391 blocks: partition grids

    ema_zero_kernel<<<nb, 256, 0, stream>>>(degi);
    ema_gemm_kernel<<<eb, 256, 0, stream>>>(x, W, bias, hbf);
    ema_degcount_kernel<<<db, 256, 0, stream>>>(ei, degi);

    ema_scan1_kernel<<<nb, 256, 0, stream>>>(degi, bsum);
    ema_scan2_kernel<<<1, 512, 0, stream>>>(bsum);
    ema_scan3_kernel<<<nb, 256, 0, stream>>>(degi, bsum, rs);
    ema_coef_kernel<<<nb, 256, 0, stream>>>(degi, coef);

    ema_hist_kernel<<<pb, 256, 0, stream>>>(ei, hcnt);
    ema_bscan_kernel<<<391, 512, 0, stream>>>(hcnt, rs);
    ema_scatter_kernel<<<pb, 256, 0, stream>>>(ei, hcnt, stage);
    ema_fillcsr_kernel<<<nb, 256, 0, stream>>>(rs, stage, csr);

    ema_passA_kernel<<<eb, 256, 0, stream>>>(degi, rs, csr, coef, hbf,
                                             m0, W1m1, W2m2, W3W4, pp);
    ema_passB_kernel<<<eb, 256, 0, stream>>>(degi, rs, csr, coef, m0,
                                             W1m1, W3W4, pp);
    ema_passC_kernel<<<eb, 256, 0, stream>>>(degi, rs, csr, coef, W1m1, W2m2);
    GraphEMALayer_18133351924067_kernel<<<eb, 256, 0, stream>>>(
        degi, rs, csr, coef, W2m2, W3W4, x, out);
}

// Round 3
// 523.402 us; speedup vs baseline: 2.1507x; 1.1287x over previous
//
#include <hip/hip_runtime.h>
#include <hip/hip_bf16.h>

// GraphEMALayer - MI355X (gfx950) - round 16: wave-structured GEMM.
// R15 counters: ema_gemm = 101 us @ 3% HBM / 14% VALU / 0 MFMA -- pure
// issue+latency bound (per-thread scalar loads, one node per wave, 64
// unprovably-uniform x-row loads per lane). Compute floor is 5.2 us
// (819 MFLOP @ 157 TF), memory floor ~6 us (38 MB). Rewrite:
//   - wave owns 8 nodes; lane = column; W[:,lane] hoisted to 64 VGPRs
//     (64 coalesced loads, W=16KB stays L1-hot);
//   - x-row pointer forced wave-uniform via readfirstlane -> s_load on
//     the SMEM pipe; fmac uses SGPR*VGPR (1 SGPR/VALU op is legal);
//   - k-order unchanged -> h bitwise identical -> absmax unchanged.
// Partition (R15 hist/bscan/scatter/fillcsr, zero contended atomics) and
// closed-form passes A-D unchanged. Workspace 60.0 MB.

static __device__ __forceinline__ float bf2f(unsigned short v) {
    union { unsigned int u; float f; } x;
    x.u = ((unsigned int)v) << 16;
    return x.f;
}

static __device__ __forceinline__ unsigned short f2bf(float f) {
    union { unsigned int u; float f; } x;
    x.f = f;
    unsigned int r = x.u + 0x7FFFu + ((x.u >> 16) & 1u);
    return (unsigned short)(r >> 16);
}

__global__ void ema_zero_kernel(int* degi) {
    int i = (int)(blockIdx.x * 256 + threadIdx.x);
    if (i < 100000) degi[i] = 0;
}

// h = x@W + b -> bf16 shadow. Wave = 8 nodes, lane = column.
__global__ void ema_gemm_kernel(const float* x, const float* W,
                                const float* bias, unsigned short* hbf) {
    int wave = (int)((blockIdx.x * 256 + threadIdx.x) >> 6);
    int lane = (int)(threadIdx.x & 63);
    int n0 = wave * 8;
    if (n0 >= 100000) return;
    float w[64];
    #pragma unroll
    for (int k = 0; k < 64; ++k) w[k] = W[k * 64 + lane];   // coalesced, L1-hot
    float bv = bias[lane];
    int nend = (n0 + 8 < 100000) ? (n0 + 8) : 100000;
    for (int n = n0; n < nend; ++n) {
        const float* xr = x + (size_t)__builtin_amdgcn_readfirstlane(n) * 64;
        float acc = bv;
        #pragma unroll
        for (int k = 0; k < 64; ++k) acc = fmaf(xr[k], w[k], acc);
        hbf[n * 64 + lane] = f2bf(acc);
    }
}

__global__ void ema_degcount_kernel(const int* ei, int* degi) {
    int e = (int)(blockIdx.x * 256 + threadIdx.x);
    if (e < 1600000) atomicAdd(&degi[ei[e]], 1);
}

__global__ void ema_scan1_kernel(const int* degi, int* bsum) {
    __shared__ int s[256];
    int i = (int)(blockIdx.x * 256 + threadIdx.x);
    int t = (int)threadIdx.x;
    s[t] = (i < 100000) ? degi[i] : 0;
    __syncthreads();
    for (int off = 128; off > 0; off >>= 1) {
        if (t < off) s[t] += s[t + off];
        __syncthreads();
    }
    if (t == 0) bsum[blockIdx.x] = s[0];
}

__global__ void ema_scan2_kernel(int* bsum) {
    __shared__ int s[512];
    int t = (int)threadIdx.x;
    int v = (t < 391) ? bsum[t] : 0;
    s[t] = v;
    __syncthreads();
    for (int off = 1; off < 512; off <<= 1) {
        int add = (t >= off) ? s[t - off] : 0;
        __syncthreads();
        s[t] += add;
        __syncthreads();
    }
    if (t < 391) bsum[t] = s[t] - v;
}

__global__ void ema_scan3_kernel(const int* degi, const int* bsum, int* rs) {
    __shared__ int s[256];
    int i = (int)(blockIdx.x * 256 + threadIdx.x);
    int t = (int)threadIdx.x;
    int v = (i < 100000) ? degi[i] : 0;
    s[t] = v;
    __syncthreads();
    for (int off = 1; off < 256; off <<= 1) {
        int add = (t >= off) ? s[t - off] : 0;
        __syncthreads();
        s[t] += add;
        __syncthreads();
    }
    if (i < 100000) rs[i] = bsum[blockIdx.x] + s[t] - v;
}

// Per-node (alpha, c): leaf -> (1, 0); else (0.5, 0.5/(deg-1+eps)).
__global__ void ema_coef_kernel(const int* degi, float2* coef) {
    int v = (int)(blockIdx.x * 256 + threadIdx.x);
    if (v >= 100000) return;
    int d = degi[v];
    float2 q;
    if (d <= 1) {
        q.x = 1.0f;
        q.y = 0.0f;
    } else {
        q.x = 0.5f;
        q.y = 0.5f / ((float)d - 1.0f + 1e-9f);
    }
    coef[v] = q;
}

// Step 1: per-block bucket histogram. Block bl owns edges
// [bl*4096, bl*4096+4096); LDS atomics only; hcnt[bucket*391 + bl].
__global__ void ema_hist_kernel(const int* ei, int* hcnt) {
    __shared__ int hist[391];
    int t = (int)threadIdx.x;
    int bl = (int)blockIdx.x;
    for (int i = t; i < 391; i += 256) hist[i] = 0;
    __syncthreads();
    int e0 = bl * 4096;
    #pragma unroll
    for (int i = 0; i < 16; ++i) {
        int e = e0 + t + i * 256;
        if (e < 1600000) {
            int dst = (e < 800000) ? ei[e + 800000] : ei[e - 800000];
            atomicAdd(&hist[dst >> 8], 1);
        }
    }
    __syncthreads();
    for (int i = t; i < 391; i += 256) hcnt[i * 391 + bl] = hist[i];
}

// Step 2: one block per bucket; exclusive scan of the 391 block counts,
// rebased at the bucket's csr segment start rs[bucket<<8]. No atomics.
__global__ void ema_bscan_kernel(int* hcnt, const int* rs) {
    __shared__ int s[512];
    int bu = (int)blockIdx.x;
    int t = (int)threadIdx.x;
    int v = (t < 391) ? hcnt[bu * 391 + t] : 0;
    s[t] = v;
    __syncthreads();
    for (int off = 1; off < 512; off <<= 1) {
        int add = (t >= off) ? s[t - off] : 0;
        __syncthreads();
        s[t] += add;
        __syncthreads();
    }
    if (t < 391) hcnt[bu * 391 + t] = rs[bu << 8] + s[t] - v;
}

// Step 3: scatter into stage at precomputed per-(bucket,block) bases.
// Re-reads the block's edges (L2-hot); LDS counters give within-run rank.
__global__ void ema_scatter_kernel(const int* ei, const int* hcnt,
                                   unsigned int* stage) {
    __shared__ int base[391];
    __shared__ int cnt[391];
    int t = (int)threadIdx.x;
    int bl = (int)blockIdx.x;
    for (int i = t; i < 391; i += 256) {
        base[i] = hcnt[i * 391 + bl];
        cnt[i] = 0;
    }
    __syncthreads();
    int e0 = bl * 4096;
    #pragma unroll
    for (int i = 0; i < 16; ++i) {
        int e = e0 + t + i * 256;
        if (e < 1600000) {
            int src = ei[e];
            int dst = (e < 800000) ? ei[e + 800000] : ei[e - 800000];
            int bu = dst >> 8;
            int slot = base[bu] + atomicAdd(&cnt[bu], 1);
            stage[slot] = ((unsigned int)(dst & 255) << 24) | (unsigned int)src;
        }
    }
}

// Step 4: one block per bucket. Staging segment + csr window are
// XCD-local (~16 KB each); per-node slots via LDS counters.
__global__ void ema_fillcsr_kernel(const int* rs, const unsigned int* stage,
                                   int* csr) {
    __shared__ int rsl[256];
    __shared__ int cnt[256];
    int b = (int)blockIdx.x;
    int t = (int)threadIdx.x;
    int node_lo = b << 8;
    int node = node_lo + t;
    rsl[t] = (node < 100000) ? rs[node] : 1600000;
    cnt[t] = 0;
    __syncthreads();
    int seg_lo = rsl[0];
    int seg_hi = (node_lo + 256 < 100000) ? rs[node_lo + 256] : 1600000;
    for (int i = seg_lo + t; i < seg_hi; i += 256) {
        unsigned int v = stage[i];
        int local = (int)(v >> 24);
        int srcn = (int)(v & 0x00FFFFFFu);
        int slot = rsl[local] + atomicAdd(&cnt[local], 1);
        csr[slot] = srcn;
    }
}

// Pass A: gather hbf rows; emit m0, W1, W2, W3a and pp=(r c P1, r c).
__global__ void ema_passA_kernel(const int* degi, const int* rs, const int* csr,
                                 const float2* coef, const unsigned short* hbf,
                                 unsigned short* m0, unsigned short* W1,
                                 unsigned short* W2, unsigned short* W3a,
                                 float2* pp) {
    int wid = (int)((blockIdx.x * 256 + threadIdx.x) >> 6);
    int c = (int)(threadIdx.x & 63);
    if (wid >= 100000) return;
    int dv = degi[wid];
    int base = wid * 64 + c;
    float hv = bf2f(hbf[base]);
    if (dv == 0) {
        m0[base] = 0;
        W1[base] = 0;
        W2[base] = 0;
        W3a[base] = f2bf(hv);   // y = h for isolated nodes
        if (c == 0) pp[wid] = make_float2(0.0f, 0.0f);
        return;
    }
    int j = rs[wid];
    int end = j + dv;
    float2 qv = coef[wid];
    float fv = qv.x * hv;
    float cv = qv.y;
    float sm = 0.0f, sS = 0.0f, sQ = 0.0f, p1 = 0.0f, p2 = 0.0f;
    for (; j + 4 <= end; j += 4) {
        int a0 = csr[j], a1 = csr[j + 1], a2 = csr[j + 2], a3 = csr[j + 3];
        float2 q0 = coef[a0], q1 = coef[a1], q2 = coef[a2], q3 = coef[a3];
        float h0 = bf2f(hbf[a0 * 64 + c]);
        float h1 = bf2f(hbf[a1 * 64 + c]);
        float h2 = bf2f(hbf[a2 * 64 + c]);
        float h3 = bf2f(hbf[a3 * 64 + c]);
        sm += (h0 + h1) + (h2 + h3);
        sS += q0.x * h0 + q1.x * h1 + q2.x * h2 + q3.x * h3;
        sQ += q0.y * h0 + q1.y * h1 + q2.y * h2 + q3.y * h3;
        p1 += (q0.y + q1.y) + (q2.y + q3.y);
        p2 += q0.y * q0.y + q1.y * q1.y + q2.y * q2.y + q3.y * q3.y;
    }
    for (; j < end; ++j) {
        int a = csr[j];
        float2 qa = coef[a];
        float ha = bf2f(hbf[a * 64 + c]);
        sm += ha;
        sS += qa.x * ha;
        sQ += qa.y * ha;
        p1 += qa.y;
        p2 += qa.y * qa.y;
    }
    float r = 0.5f / ((float)dv + 1e-9f);
    float w1 = sS - hv * p1;
    float w2 = sS - fv * p1 - cv * p1 * sm + cv * sQ;
    float w3 = 0.5f * hv + r * (sS - fv * p1 + 0.5f * cv * sQ - cv * hv * p2);
    m0[base] = f2bf(sm);
    W1[base] = f2bf(w1);
    W2[base] = f2bf(w2);
    W3a[base] = f2bf(w3);
    if (c == 0) pp[wid] = make_float2(r * cv * p1, r * cv);
}

// Pass B: gather m0 rows; m1 = W1 + sum c_a m0[a] (in place over W1);
// W4 = W3a - pp.x*m1 + pp.y*U, U = sum c_a^2 m0[a] (in place over W3a).
__global__ void ema_passB_kernel(const int* degi, const int* rs, const int* csr,
                                 const float2* coef, const unsigned short* m0,
                                 unsigned short* W1m1, unsigned short* W3W4,
                                 const float2* pp) {
    int wid = (int)((blockIdx.x * 256 + threadIdx.x) >> 6);
    int c = (int)(threadIdx.x & 63);
    if (wid >= 100000) return;
    int dv = degi[wid];
    if (dv == 0) return;   // slots already hold m1=0, W4=h from pass A
    int base = wid * 64 + c;
    int j = rs[wid];
    int end = j + dv;
    float t1 = 0.0f, t2 = 0.0f;
    for (; j + 4 <= end; j += 4) {
        int a0 = csr[j], a1 = csr[j + 1], a2 = csr[j + 2], a3 = csr[j + 3];
        float c0 = coef[a0].y, c1 = coef[a1].y, c2 = coef[a2].y, c3 = coef[a3].y;
        float m0v = bf2f(m0[a0 * 64 + c]);
        float m1v = bf2f(m0[a1 * 64 + c]);
        float m2v = bf2f(m0[a2 * 64 + c]);
        float m3v = bf2f(m0[a3 * 64 + c]);
        t1 += c0 * m0v + c1 * m1v + c2 * m2v + c3 * m3v;
        t2 += c0 * c0 * m0v + c1 * c1 * m1v + c2 * c2 * m2v + c3 * c3 * m3v;
    }
    for (; j < end; ++j) {
        int a = csr[j];
        float ca = coef[a].y;
        float mv = bf2f(m0[a * 64 + c]);
        t1 += ca * mv;
        t2 += ca * ca * mv;
    }
    float2 ppv = pp[wid];
    float m1 = bf2f(W1m1[base]) + t1;
    float w4 = bf2f(W3W4[base]) - ppv.x * m1 + ppv.y * t2;
    W1m1[base] = f2bf(m1);
    W3W4[base] = f2bf(w4);
}

// Pass C: gather m1 rows; m2 = W2 + sum c_a m1[a] (in place over W2).
__global__ void ema_passC_kernel(const int* degi, const int* rs, const int* csr,
                                 const float2* coef, const unsigned short* m1,
                                 unsigned short* W2m2) {
    int wid = (int)((blockIdx.x * 256 + threadIdx.x) >> 6);
    int c = (int)(threadIdx.x & 63);
    if (wid >= 100000) return;
    int dv = degi[wid];
    if (dv == 0) return;   // slot already holds m2=0
    int base = wid * 64 + c;
    int j = rs[wid];
    int end = j + dv;
    float t = 0.0f;
    for (; j + 4 <= end; j += 4) {
        int a0 = csr[j], a1 = csr[j + 1], a2 = csr[j + 2], a3 = csr[j + 3];
        float c0 = coef[a0].y, c1 = coef[a1].y, c2 = coef[a2].y, c3 = coef[a3].y;
        float m0v = bf2f(m1[a0 * 64 + c]);
        float m1v = bf2f(m1[a1 * 64 + c]);
        float m2v = bf2f(m1[a2 * 64 + c]);
        float m3v = bf2f(m1[a3 * 64 + c]);
        t += c0 * m0v + c1 * m1v + c2 * m2v + c3 * m3v;
    }
    for (; j < end; ++j) {
        int a = csr[j];
        t += coef[a].y * bf2f(m1[a * 64 + c]);
    }
    float m2v = bf2f(W2m2[base]) + t;
    W2m2[base] = f2bf(m2v);
}

// Pass D (identifier kernel): gather m2 rows; y = W4 + r*sum c_a m2[a];
// out = x + relu(y). Overwrites all of d_out (m0 region is dead).
__global__ void GraphEMALayer_18133351924067_kernel(
    const int* degi, const int* rs, const int* csr, const float2* coef,
    const unsigned short* m2, const unsigned short* W4,
    const float* x, float* out) {
    int wid = (int)((blockIdx.x * 256 + threadIdx.x) >> 6);
    int c = (int)(threadIdx.x & 63);
    if (wid >= 100000) return;
    int dv = degi[wid];
    int base = wid * 64 + c;
    float xv = x[base];
    float y = bf2f(W4[base]);
    if (dv > 0) {
        int j = rs[wid];
        int end = j + dv;
        float t = 0.0f;
        for (; j + 4 <= end; j += 4) {
            int a0 = csr[j], a1 = csr[j + 1], a2 = csr[j + 2], a3 = csr[j + 3];
            float c0 = coef[a0].y, c1 = coef[a1].y, c2 = coef[a2].y, c3 = coef[a3].y;
            float m0v = bf2f(m2[a0 * 64 + c]);
            float m1v = bf2f(m2[a1 * 64 + c]);
            float m2v = bf2f(m2[a2 * 64 + c]);
            float m3v = bf2f(m2[a3 * 64 + c]);
            t += c0 * m0v + c1 * m1v + c2 * m2v + c3 * m3v;
        }
        for (; j < end; ++j) {
            int a = csr[j];
            t += coef[a].y * bf2f(m2[a * 64 + c]);
        }
        float r = 0.5f / ((float)dv + 1e-9f);
        y += r * t;
    }
    if (y < 0.0f) y = 0.0f;
    out[base] = xv + y;
}

extern "C" void kernel_launch(void* const* d_in, const int* in_sizes, int n_in,
                              void* d_out, int out_size, void* d_ws, size_t ws_size,
                              hipStream_t stream) {
    (void)in_sizes; (void)n_in; (void)out_size; (void)ws_size;

    const float* x    = (const float*)d_in[0];
    const int*   ei   = (const int*)d_in[1];
    const float* W    = (const float*)d_in[2];
    const float* bias = (const float*)d_in[3];
    float* out = (float*)d_out;
    unsigned short* m0 = (unsigned short*)d_out;   // first 12.8 MB, dead before D

    char* ws = (char*)d_ws;
    unsigned short* hbf  = (unsigned short*)(ws);             // 12,800,000 B
    unsigned short* W1m1 = (unsigned short*)(ws + 12800000);  // 12,800,000 B
    unsigned short* W2m2 = (unsigned short*)(ws + 25600000);  // 12,800,000 B
    unsigned short* W3W4 = (unsigned short*)(ws + 38400000);  // 12,800,000 B
    int* degi = (int*)(ws + 51200000);                        //    400,000 B
    int* rs   = (int*)(ws + 51600000);                        //    400,000 B
    float2* coef = (float2*)(ws + 52000000);                  //    800,000 B
    float2* pp   = (float2*)(ws + 52800000);                  //    800,000 B
    int* csr  = (int*)(ws + 53600000);                        //  6,400,000 B
    int* bsum = (int*)(ws + 60000000);                        //      4,096 B

    // CSR-build scratch, both dead before pass A writes them:
    unsigned int* stage = (unsigned int*)(ws + 12800000);     // aliases W1m1, 6.4 MB
    int* hcnt = (int*)(ws + 25600000);                        // aliases W2m2, 611,524 B

    int eb = (100000 * 64 + 255) / 256;   // 25000 blocks: wave-per-node grids
    int nb = (100000 + 255) / 256;        //   391 blocks: per-node grids
    int db = (1600000 + 255) / 256;       //  6250 blocks: per-edge grids
    int pb = (1600000 + 4095) / 4096;     //   391 blocks: partition grids
    int gb = (100000 + 31) / 32;          //  3125 blocks: gemm (32 nodes/block)

    ema_zero_kernel<<<nb, 256, 0, stream>>>(degi);
    ema_gemm_kernel<<<gb, 256, 0, stream>>>(x, W, bias, hbf);
    ema_degcount_kernel<<<db, 256, 0, stream>>>(ei, degi);

    ema_scan1_kernel<<<nb, 256, 0, stream>>>(degi, bsum);
    ema_scan2_kernel<<<1, 512, 0, stream>>>(bsum);
    ema_scan3_kernel<<<nb, 256, 0, stream>>>(degi, bsum, rs);
    ema_coef_kernel<<<nb, 256, 0, stream>>>(degi, coef);

    ema_hist_kernel<<<pb, 256, 0, stream>>>(ei, hcnt);
    ema_bscan_kernel<<<391, 512, 0, stream>>>(hcnt, rs);
    ema_scatter_kernel<<<pb, 256, 0, stream>>>(ei, hcnt, stage);
    ema_fillcsr_kernel<<<nb, 256, 0, stream>>>(rs, stage, csr);

    ema_passA_kernel<<<eb, 256, 0, stream>>>(degi, rs, csr, coef, hbf,
                                             m0, W1m1, W2m2, W3W4, pp);
    ema_passB_kernel<<<eb, 256, 0, stream>>>(degi, rs, csr, coef, m0,
                                             W1m1, W3W4, pp);
    ema_passC_kernel<<<eb, 256, 0, stream>>>(degi, rs, csr, coef, W1m1, W2m2);
    GraphEMALayer_18133351924067_kernel<<<eb, 256, 0, stream>>>(
        degi, rs, csr, coef, W2m2, W3W4, x, out);
}

// Round 4
// 445.141 us; speedup vs baseline: 2.5288x; 1.1758x over previous
//
#include <hip/hip_runtime.h>
#include <hip/hip_bf16.h>

// GraphEMALayer - MI355X (gfx950) - round 17: scalarized gather loops +
// coefficient packed into csr.
// R16 counters: passA = 95.6 us @ 20% HBM / 49% VALU -- gather-latency
// bound. Per edge the wave issued 3 dependent VMEM ops: csr[j] (64-lane
// broadcast), coef[a] (dependent uniform gather), hbf row (the real one).
// Fix:
//   - csr entry now packs (min(deg-1,32767)<<17) | idx (idx < 2^17).
//     c_a = 0.5*rcp((float)(deg-1)) recomputed per edge (<=1 ulp vs exact
//     div: (float)d-1+1e-9 rounds to d-1 exactly); leaf -> c=0 via
//     cndmask; alpha = dm1?0.5:1.0 is a scalar select. Dependent coef
//     gather GONE from all 4 passes.
//   - loop induction forced scalar via readfirstlane(rs[wid]) and
//     __restrict__ everywhere -> csr loads go to the SMEM pipe (s_load),
//     leaving ONE per-edge VMEM gather (the 128 B row).
// fillcsr now gathers degi[src] (400 KB, L2-resident) to build the pack.
// Partition + closed-form passes otherwise unchanged. Workspace 60.0 MB.

static __device__ __forceinline__ float bf2f(unsigned short v) {
    union { unsigned int u; float f; } x;
    x.u = ((unsigned int)v) << 16;
    return x.f;
}

static __device__ __forceinline__ unsigned short f2bf(float f) {
    union { unsigned int u; float f; } x;
    x.f = f;
    unsigned int r = x.u + 0x7FFFu + ((x.u >> 16) & 1u);
    return (unsigned short)(r >> 16);
}

// c from packed dm1: 0.5*rcp(dm1); exact 0 for leaves (dm1==0).
static __device__ __forceinline__ float edge_c(int dm1) {
    float fd = (float)dm1;
    float raw = 0.5f * __builtin_amdgcn_rcpf(fd);
    return (fd == 0.0f) ? 0.0f : raw;
}

__global__ void ema_zero_kernel(int* degi) {
    int i = (int)(blockIdx.x * 256 + threadIdx.x);
    if (i < 100000) degi[i] = 0;
}

// h = x@W + b -> bf16 shadow. Wave = 8 nodes, lane = column.
__global__ void ema_gemm_kernel(const float* __restrict__ x, const float* __restrict__ W,
                                const float* __restrict__ bias, unsigned short* __restrict__ hbf) {
    int wave = (int)((blockIdx.x * 256 + threadIdx.x) >> 6);
    int lane = (int)(threadIdx.x & 63);
    int n0 = wave * 8;
    if (n0 >= 100000) return;
    float w[64];
    #pragma unroll
    for (int k = 0; k < 64; ++k) w[k] = W[k * 64 + lane];   // coalesced, L1-hot
    float bv = bias[lane];
    int nend = (n0 + 8 < 100000) ? (n0 + 8) : 100000;
    for (int n = n0; n < nend; ++n) {
        const float* xr = x + (size_t)__builtin_amdgcn_readfirstlane(n) * 64;
        float acc = bv;
        #pragma unroll
        for (int k = 0; k < 64; ++k) acc = fmaf(xr[k], w[k], acc);
        hbf[n * 64 + lane] = f2bf(acc);
    }
}

__global__ void ema_degcount_kernel(const int* ei, int* degi) {
    int e = (int)(blockIdx.x * 256 + threadIdx.x);
    if (e < 1600000) atomicAdd(&degi[ei[e]], 1);
}

__global__ void ema_scan1_kernel(const int* degi, int* bsum) {
    __shared__ int s[256];
    int i = (int)(blockIdx.x * 256 + threadIdx.x);
    int t = (int)threadIdx.x;
    s[t] = (i < 100000) ? degi[i] : 0;
    __syncthreads();
    for (int off = 128; off > 0; off >>= 1) {
        if (t < off) s[t] += s[t + off];
        __syncthreads();
    }
    if (t == 0) bsum[blockIdx.x] = s[0];
}

__global__ void ema_scan2_kernel(int* bsum) {
    __shared__ int s[512];
    int t = (int)threadIdx.x;
    int v = (t < 391) ? bsum[t] : 0;
    s[t] = v;
    __syncthreads();
    for (int off = 1; off < 512; off <<= 1) {
        int add = (t >= off) ? s[t - off] : 0;
        __syncthreads();
        s[t] += add;
        __syncthreads();
    }
    if (t < 391) bsum[t] = s[t] - v;
}

__global__ void ema_scan3_kernel(const int* degi, const int* bsum, int* rs) {
    __shared__ int s[256];
    int i = (int)(blockIdx.x * 256 + threadIdx.x);
    int t = (int)threadIdx.x;
    int v = (i < 100000) ? degi[i] : 0;
    s[t] = v;
    __syncthreads();
    for (int off = 1; off < 256; off <<= 1) {
        int add = (t >= off) ? s[t - off] : 0;
        __syncthreads();
        s[t] += add;
        __syncthreads();
    }
    if (i < 100000) rs[i] = bsum[blockIdx.x] + s[t] - v;
}

// Per-node (alpha, c): leaf -> (1, 0); else (0.5, 0.5/(deg-1+eps)).
// (Own-node coefficients for pass A; neighbor coefficients come packed.)
__global__ void ema_coef_kernel(const int* degi, float2* coef) {
    int v = (int)(blockIdx.x * 256 + threadIdx.x);
    if (v >= 100000) return;
    int d = degi[v];
    float2 q;
    if (d <= 1) {
        q.x = 1.0f;
        q.y = 0.0f;
    } else {
        q.x = 0.5f;
        q.y = 0.5f / ((float)d - 1.0f + 1e-9f);
    }
    coef[v] = q;
}

// Step 1: per-block bucket histogram. Block bl owns edges
// [bl*4096, bl*4096+4096); LDS atomics only; hcnt[bucket*391 + bl].
__global__ void ema_hist_kernel(const int* ei, int* hcnt) {
    __shared__ int hist[391];
    int t = (int)threadIdx.x;
    int bl = (int)blockIdx.x;
    for (int i = t; i < 391; i += 256) hist[i] = 0;
    __syncthreads();
    int e0 = bl * 4096;
    #pragma unroll
    for (int i = 0; i < 16; ++i) {
        int e = e0 + t + i * 256;
        if (e < 1600000) {
            int dst = (e < 800000) ? ei[e + 800000] : ei[e - 800000];
            atomicAdd(&hist[dst >> 8], 1);
        }
    }
    __syncthreads();
    for (int i = t; i < 391; i += 256) hcnt[i * 391 + bl] = hist[i];
}

// Step 2: one block per bucket; exclusive scan of the 391 block counts,
// rebased at the bucket's csr segment start rs[bucket<<8]. No atomics.
__global__ void ema_bscan_kernel(int* hcnt, const int* rs) {
    __shared__ int s[512];
    int bu = (int)blockIdx.x;
    int t = (int)threadIdx.x;
    int v = (t < 391) ? hcnt[bu * 391 + t] : 0;
    s[t] = v;
    __syncthreads();
    for (int off = 1; off < 512; off <<= 1) {
        int add = (t >= off) ? s[t - off] : 0;
        __syncthreads();
        s[t] += add;
        __syncthreads();
    }
    if (t < 391) hcnt[bu * 391 + t] = rs[bu << 8] + s[t] - v;
}

// Step 3: scatter into stage at precomputed per-(bucket,block) bases.
// Re-reads the block's edges (L2-hot); LDS counters give within-run rank.
__global__ void ema_scatter_kernel(const int* ei, const int* hcnt,
                                   unsigned int* stage) {
    __shared__ int base[391];
    __shared__ int cnt[391];
    int t = (int)threadIdx.x;
    int bl = (int)blockIdx.x;
    for (int i = t; i < 391; i += 256) {
        base[i] = hcnt[i * 391 + bl];
        cnt[i] = 0;
    }
    __syncthreads();
    int e0 = bl * 4096;
    #pragma unroll
    for (int i = 0; i < 16; ++i) {
        int e = e0 + t + i * 256;
        if (e < 1600000) {
            int src = ei[e];
            int dst = (e < 800000) ? ei[e + 800000] : ei[e - 800000];
            int bu = dst >> 8;
            int slot = base[bu] + atomicAdd(&cnt[bu], 1);
            stage[slot] = ((unsigned int)(dst & 255) << 24) | (unsigned int)src;
        }
    }
}

// Step 4: one block per bucket; LDS per-node slots; writes PACKED csr:
// (min(deg[src]-1,32767)<<17) | src.  degi gather is L2-resident (400 KB).
__global__ void ema_fillcsr_kernel(const int* __restrict__ rs,
                                   const unsigned int* __restrict__ stage,
                                   const int* __restrict__ degi,
                                   int* __restrict__ csr) {
    __shared__ int rsl[256];
    __shared__ int cnt[256];
    int b = (int)blockIdx.x;
    int t = (int)threadIdx.x;
    int node_lo = b << 8;
    int node = node_lo + t;
    rsl[t] = (node < 100000) ? rs[node] : 1600000;
    cnt[t] = 0;
    __syncthreads();
    int seg_lo = rsl[0];
    int seg_hi = (node_lo + 256 < 100000) ? rs[node_lo + 256] : 1600000;
    for (int i = seg_lo + t; i < seg_hi; i += 256) {
        unsigned int v = stage[i];
        int local = (int)(v >> 24);
        int srcn = (int)(v & 0x00FFFFFFu);
        int dm1 = degi[srcn] - 1;
        if (dm1 < 0) dm1 = 0;
        if (dm1 > 32767) dm1 = 32767;
        int slot = rsl[local] + atomicAdd(&cnt[local], 1);
        csr[slot] = (dm1 << 17) | srcn;
    }
}

// Pass A: gather hbf rows; emit m0, W1, W2, W3a and pp=(r c P1, r c).
__global__ void ema_passA_kernel(const int* __restrict__ degi, const int* __restrict__ rs,
                                 const int* __restrict__ csr, const float2* __restrict__ coef,
                                 const unsigned short* __restrict__ hbf,
                                 unsigned short* __restrict__ m0, unsigned short* __restrict__ W1,
                                 unsigned short* __restrict__ W2, unsigned short* __restrict__ W3a,
                                 float2* __restrict__ pp) {
    int wid = (int)((blockIdx.x * 256 + threadIdx.x) >> 6);
    int c = (int)(threadIdx.x & 63);
    if (wid >= 100000) return;
    int dv = __builtin_amdgcn_readfirstlane(degi[wid]);
    int base = wid * 64 + c;
    float hv = bf2f(hbf[base]);
    if (dv == 0) {
        m0[base] = 0;
        W1[base] = 0;
        W2[base] = 0;
        W3a[base] = f2bf(hv);   // y = h for isolated nodes
        if (c == 0) pp[wid] = make_float2(0.0f, 0.0f);
        return;
    }
    int j = __builtin_amdgcn_readfirstlane(rs[wid]);
    int end = j + dv;
    float2 qv = coef[wid];
    float fv = qv.x * hv;
    float cv = qv.y;
    float sm = 0.0f, sS = 0.0f, sQ = 0.0f, p1 = 0.0f, p2 = 0.0f;
    for (; j + 4 <= end; j += 4) {
        unsigned int w0 = (unsigned int)csr[j];
        unsigned int w1 = (unsigned int)csr[j + 1];
        unsigned int w2 = (unsigned int)csr[j + 2];
        unsigned int w3 = (unsigned int)csr[j + 3];
        int a0 = (int)(w0 & 0x1FFFFu), d0 = (int)(w0 >> 17);
        int a1 = (int)(w1 & 0x1FFFFu), d1 = (int)(w1 >> 17);
        int a2 = (int)(w2 & 0x1FFFFu), d2 = (int)(w2 >> 17);
        int a3 = (int)(w3 & 0x1FFFFu), d3 = (int)(w3 >> 17);
        float h0 = bf2f(hbf[a0 * 64 + c]);
        float h1 = bf2f(hbf[a1 * 64 + c]);
        float h2 = bf2f(hbf[a2 * 64 + c]);
        float h3 = bf2f(hbf[a3 * 64 + c]);
        float c0 = edge_c(d0), c1 = edge_c(d1), c2 = edge_c(d2), c3 = edge_c(d3);
        float al0 = d0 ? 0.5f : 1.0f;
        float al1 = d1 ? 0.5f : 1.0f;
        float al2 = d2 ? 0.5f : 1.0f;
        float al3 = d3 ? 0.5f : 1.0f;
        sm += (h0 + h1) + (h2 + h3);
        sS += al0 * h0 + al1 * h1 + al2 * h2 + al3 * h3;
        sQ += c0 * h0 + c1 * h1 + c2 * h2 + c3 * h3;
        p1 += (c0 + c1) + (c2 + c3);
        p2 += c0 * c0 + c1 * c1 + c2 * c2 + c3 * c3;
    }
    for (; j < end; ++j) {
        unsigned int w0 = (unsigned int)csr[j];
        int a = (int)(w0 & 0x1FFFFu), d0 = (int)(w0 >> 17);
        float ha = bf2f(hbf[a * 64 + c]);
        float ca = edge_c(d0);
        float ala = d0 ? 0.5f : 1.0f;
        sm += ha;
        sS += ala * ha;
        sQ += ca * ha;
        p1 += ca;
        p2 += ca * ca;
    }
    float r = 0.5f / ((float)dv + 1e-9f);
    float w1o = sS - hv * p1;
    float w2o = sS - fv * p1 - cv * p1 * sm + cv * sQ;
    float w3o = 0.5f * hv + r * (sS - fv * p1 + 0.5f * cv * sQ - cv * hv * p2);
    m0[base] = f2bf(sm);
    W1[base] = f2bf(w1o);
    W2[base] = f2bf(w2o);
    W3a[base] = f2bf(w3o);
    if (c == 0) pp[wid] = make_float2(r * cv * p1, r * cv);
}

// Pass B: gather m0 rows; m1 = W1 + sum c_a m0[a] (in place over W1);
// W4 = W3a - pp.x*m1 + pp.y*U, U = sum c_a^2 m0[a] (in place over W3a).
__global__ void ema_passB_kernel(const int* __restrict__ degi, const int* __restrict__ rs,
                                 const int* __restrict__ csr,
                                 const unsigned short* __restrict__ m0,
                                 unsigned short* __restrict__ W1m1, unsigned short* __restrict__ W3W4,
                                 const float2* __restrict__ pp) {
    int wid = (int)((blockIdx.x * 256 + threadIdx.x) >> 6);
    int c = (int)(threadIdx.x & 63);
    if (wid >= 100000) return;
    int dv = __builtin_amdgcn_readfirstlane(degi[wid]);
    if (dv == 0) return;   // slots already hold m1=0, W4=h from pass A
    int base = wid * 64 + c;
    int j = __builtin_amdgcn_readfirstlane(rs[wid]);
    int end = j + dv;
    float t1 = 0.0f, t2 = 0.0f;
    for (; j + 4 <= end; j += 4) {
        unsigned int w0 = (unsigned int)csr[j];
        unsigned int w1 = (unsigned int)csr[j + 1];
        unsigned int w2 = (unsigned int)csr[j + 2];
        unsigned int w3 = (unsigned int)csr[j + 3];
        int a0 = (int)(w0 & 0x1FFFFu), d0 = (int)(w0 >> 17);
        int a1 = (int)(w1 & 0x1FFFFu), d1 = (int)(w1 >> 17);
        int a2 = (int)(w2 & 0x1FFFFu), d2 = (int)(w2 >> 17);
        int a3 = (int)(w3 & 0x1FFFFu), d3 = (int)(w3 >> 17);
        float m0v = bf2f(m0[a0 * 64 + c]);
        float m1v = bf2f(m0[a1 * 64 + c]);
        float m2v = bf2f(m0[a2 * 64 + c]);
        float m3v = bf2f(m0[a3 * 64 + c]);
        float c0 = edge_c(d0), c1 = edge_c(d1), c2 = edge_c(d2), c3 = edge_c(d3);
        t1 += c0 * m0v + c1 * m1v + c2 * m2v + c3 * m3v;
        t2 += c0 * c0 * m0v + c1 * c1 * m1v + c2 * c2 * m2v + c3 * c3 * m3v;
    }
    for (; j < end; ++j) {
        unsigned int w0 = (unsigned int)csr[j];
        int a = (int)(w0 & 0x1FFFFu), d0 = (int)(w0 >> 17);
        float ca = edge_c(d0);
        float mv = bf2f(m0[a * 64 + c]);
        t1 += ca * mv;
        t2 += ca * ca * mv;
    }
    float2 ppv = pp[wid];
    float m1 = bf2f(W1m1[base]) + t1;
    float w4 = bf2f(W3W4[base]) - ppv.x * m1 + ppv.y * t2;
    W1m1[base] = f2bf(m1);
    W3W4[base] = f2bf(w4);
}

// Pass C: gather m1 rows; m2 = W2 + sum c_a m1[a] (in place over W2).
__global__ void ema_passC_kernel(const int* __restrict__ degi, const int* __restrict__ rs,
                                 const int* __restrict__ csr,
                                 const unsigned short* __restrict__ m1,
                                 unsigned short* __restrict__ W2m2) {
    int wid = (int)((blockIdx.x * 256 + threadIdx.x) >> 6);
    int c = (int)(threadIdx.x & 63);
    if (wid >= 100000) return;
    int dv = __builtin_amdgcn_readfirstlane(degi[wid]);
    if (dv == 0) return;   // slot already holds m2=0
    int base = wid * 64 + c;
    int j = __builtin_amdgcn_readfirstlane(rs[wid]);
    int end = j + dv;
    float t = 0.0f;
    for (; j + 4 <= end; j += 4) {
        unsigned int w0 = (unsigned int)csr[j];
        unsigned int w1 = (unsigned int)csr[j + 1];
        unsigned int w2 = (unsigned int)csr[j + 2];
        unsigned int w3 = (unsigned int)csr[j + 3];
        int a0 = (int)(w0 & 0x1FFFFu), d0 = (int)(w0 >> 17);
        int a1 = (int)(w1 & 0x1FFFFu), d1 = (int)(w1 >> 17);
        int a2 = (int)(w2 & 0x1FFFFu), d2 = (int)(w2 >> 17);
        int a3 = (int)(w3 & 0x1FFFFu), d3 = (int)(w3 >> 17);
        float m0v = bf2f(m1[a0 * 64 + c]);
        float m1v = bf2f(m1[a1 * 64 + c]);
        float m2v = bf2f(m1[a2 * 64 + c]);
        float m3v = bf2f(m1[a3 * 64 + c]);
        float c0 = edge_c(d0), c1 = edge_c(d1), c2 = edge_c(d2), c3 = edge_c(d3);
        t += c0 * m0v + c1 * m1v + c2 * m2v + c3 * m3v;
    }
    for (; j < end; ++j) {
        unsigned int w0 = (unsigned int)csr[j];
        int a = (int)(w0 & 0x1FFFFu), d0 = (int)(w0 >> 17);
        t += edge_c(d0) * bf2f(m1[a * 64 + c]);
    }
    float m2v = bf2f(W2m2[base]) + t;
    W2m2[base] = f2bf(m2v);
}

// Pass D (identifier kernel): gather m2 rows; y = W4 + r*sum c_a m2[a];
// out = x + relu(y). Overwrites all of d_out (m0 region is dead).
__global__ void GraphEMALayer_18133351924067_kernel(
    const int* __restrict__ degi, const int* __restrict__ rs,
    const int* __restrict__ csr,
    const unsigned short* __restrict__ m2, const unsigned short* __restrict__ W4,
    const float* __restrict__ x, float* __restrict__ out) {
    int wid = (int)((blockIdx.x * 256 + threadIdx.x) >> 6);
    int c = (int)(threadIdx.x & 63);
    if (wid >= 100000) return;
    int dv = __builtin_amdgcn_readfirstlane(degi[wid]);
    int base = wid * 64 + c;
    float xv = x[base];
    float y = bf2f(W4[base]);
    if (dv > 0) {
        int j = __builtin_amdgcn_readfirstlane(rs[wid]);
        int end = j + dv;
        float t = 0.0f;
        for (; j + 4 <= end; j += 4) {
            unsigned int w0 = (unsigned int)csr[j];
            unsigned int w1 = (unsigned int)csr[j + 1];
            unsigned int w2 = (unsigned int)csr[j + 2];
            unsigned int w3 = (unsigned int)csr[j + 3];
            int a0 = (int)(w0 & 0x1FFFFu), d0 = (int)(w0 >> 17);
            int a1 = (int)(w1 & 0x1FFFFu), d1 = (int)(w1 >> 17);
            int a2 = (int)(w2 & 0x1FFFFu), d2 = (int)(w2 >> 17);
            int a3 = (int)(w3 & 0x1FFFFu), d3 = (int)(w3 >> 17);
            float m0v = bf2f(m2[a0 * 64 + c]);
            float m1v = bf2f(m2[a1 * 64 + c]);
            float m2v = bf2f(m2[a2 * 64 + c]);
            float m3v = bf2f(m2[a3 * 64 + c]);
            float c0 = edge_c(d0), c1 = edge_c(d1), c2 = edge_c(d2), c3 = edge_c(d3);
            t += c0 * m0v + c1 * m1v + c2 * m2v + c3 * m3v;
        }
        for (; j < end; ++j) {
            unsigned int w0 = (unsigned int)csr[j];
            int a = (int)(w0 & 0x1FFFFu), d0 = (int)(w0 >> 17);
            t += edge_c(d0) * bf2f(m2[a * 64 + c]);
        }
        float r = 0.5f / ((float)dv + 1e-9f);
        y += r * t;
    }
    if (y < 0.0f) y = 0.0f;
    out[base] = xv + y;
}

extern "C" void kernel_launch(void* const* d_in, const int* in_sizes, int n_in,
                              void* d_out, int out_size, void* d_ws, size_t ws_size,
                              hipStream_t stream) {
    (void)in_sizes; (void)n_in; (void)out_size; (void)ws_size;

    const float* x    = (const float*)d_in[0];
    const int*   ei   = (const int*)d_in[1];
    const float* W    = (const float*)d_in[2];
    const float* bias = (const float*)d_in[3];
    float* out = (float*)d_out;
    unsigned short* m0 = (unsigned short*)d_out;   // first 12.8 MB, dead before D

    char* ws = (char*)d_ws;
    unsigned short* hbf  = (unsigned short*)(ws);             // 12,800,000 B
    unsigned short* W1m1 = (unsigned short*)(ws + 12800000);  // 12,800,000 B
    unsigned short* W2m2 = (unsigned short*)(ws + 25600000);  // 12,800,000 B
    unsigned short* W3W4 = (unsigned short*)(ws + 38400000);  // 12,800,000 B
    int* degi = (int*)(ws + 51200000);                        //    400,000 B
    int* rs   = (int*)(ws + 51600000);                        //    400,000 B
    float2* coef = (float2*)(ws + 52000000);                  //    800,000 B
    float2* pp   = (float2*)(ws + 52800000);                  //    800,000 B
    int* csr  = (int*)(ws + 53600000);                        //  6,400,000 B
    int* bsum = (int*)(ws + 60000000);                        //      4,096 B

    // CSR-build scratch, both dead before pass A writes them:
    unsigned int* stage = (unsigned int*)(ws + 12800000);     // aliases W1m1, 6.4 MB
    int* hcnt = (int*)(ws + 25600000);                        // aliases W2m2, 611,524 B

    int eb = (100000 * 64 + 255) / 256;   // 25000 blocks: wave-per-node grids
    int nb = (100000 + 255) / 256;        //   391 blocks: per-node grids
    int db = (1600000 + 255) / 256;       //  6250 blocks: per-edge grids
    int pb = (1600000 + 4095) / 4096;     //   391 blocks: partition grids
    int gb = (100000 + 31) / 32;          //  3125 blocks: gemm (32 nodes/block)

    ema_zero_kernel<<<nb, 256, 0, stream>>>(degi);
    ema_gemm_kernel<<<gb, 256, 0, stream>>>(x, W, bias, hbf);
    ema_degcount_kernel<<<db, 256, 0, stream>>>(ei, degi);

    ema_scan1_kernel<<<nb, 256, 0, stream>>>(degi, bsum);
    ema_scan2_kernel<<<1, 512, 0, stream>>>(bsum);
    ema_scan3_kernel<<<nb, 256, 0, stream>>>(degi, bsum, rs);
    ema_coef_kernel<<<nb, 256, 0, stream>>>(degi, coef);

    ema_hist_kernel<<<pb, 256, 0, stream>>>(ei, hcnt);
    ema_bscan_kernel<<<391, 512, 0, stream>>>(hcnt, rs);
    ema_scatter_kernel<<<pb, 256, 0, stream>>>(ei, hcnt, stage);
    ema_fillcsr_kernel<<<nb, 256, 0, stream>>>(rs, stage, degi, csr);

    ema_passA_kernel<<<eb, 256, 0, stream>>>(degi, rs, csr, coef, hbf,
                                             m0, W1m1, W2m2, W3W4, pp);
    ema_passB_kernel<<<eb, 256, 0, stream>>>(degi, rs, csr, m0,
                                             W1m1, W3W4, pp);
    ema_passC_kernel<<<eb, 256, 0, stream>>>(degi, rs, csr, W1m1, W2m2);
    GraphEMALayer_18133351924067_kernel<<<eb, 256, 0, stream>>>(
        degi, rs, csr, W2m2, W3W4, x, out);
}

// Round 5
// 377.235 us; speedup vs baseline: 2.9840x; 1.1800x over previous
//
#include <hip/hip_runtime.h>
#include <hip/hip_bf16.h>

// GraphEMALayer - MI355X (gfx950) - round 18: atomic-free degree/offset build.
// R17 counters: ema_degcount = 65.9 us, WRITE_SIZE 49.9 MB for a 400 KB
// array -- 1.6M device-scope atomicAdds x ~32 B coherence traffic each.
// The bucketed partition already counts everything; derive degrees from it:
//   ema_hist        per-block bucket histogram (no degi needed)      [as R17]
//   ema_bscan_row   row-wise exclusive scan of hcnt + row totals
//   ema_bscan_base  1-block scan of 391 totals -> bbase[] (== old rs[bu<<8])
//   ema_scatter     slot = (hcnt row base + bbase[bu]) + LDS rank    [stage
//                   is bitwise identical to R17's]
//   ema_fillcsr_count  1 block/bucket: LDS-count 256 local ids over the
//                   stage segment, block scan -> degi[] + rs[]. NO atomics.
//   ema_fillcsr_write  as R17's fillcsr (packed (deg-1)<<17|idx).
// Killed: ema_zero, ema_degcount, ema_scan1/2/3, ema_coef (passA computes
// own-node (alpha,c) inline from dv -- same expression, bit-identical).
// All downstream values bitwise identical to R17. Workspace 60.0 MB.

static __device__ __forceinline__ float bf2f(unsigned short v) {
    union { unsigned int u; float f; } x;
    x.u = ((unsigned int)v) << 16;
    return x.f;
}

static __device__ __forceinline__ unsigned short f2bf(float f) {
    union { unsigned int u; float f; } x;
    x.f = f;
    unsigned int r = x.u + 0x7FFFu + ((x.u >> 16) & 1u);
    return (unsigned short)(r >> 16);
}

// c from packed dm1: 0.5*rcp(dm1); exact 0 for leaves (dm1==0).
static __device__ __forceinline__ float edge_c(int dm1) {
    float fd = (float)dm1;
    float raw = 0.5f * __builtin_amdgcn_rcpf(fd);
    return (fd == 0.0f) ? 0.0f : raw;
}

// h = x@W + b -> bf16 shadow. Wave = 8 nodes, lane = column.
__global__ void ema_gemm_kernel(const float* __restrict__ x, const float* __restrict__ W,
                                const float* __restrict__ bias, unsigned short* __restrict__ hbf) {
    int wave = (int)((blockIdx.x * 256 + threadIdx.x) >> 6);
    int lane = (int)(threadIdx.x & 63);
    int n0 = wave * 8;
    if (n0 >= 100000) return;
    float w[64];
    #pragma unroll
    for (int k = 0; k < 64; ++k) w[k] = W[k * 64 + lane];   // coalesced, L1-hot
    float bv = bias[lane];
    int nend = (n0 + 8 < 100000) ? (n0 + 8) : 100000;
    for (int n = n0; n < nend; ++n) {
        const float* xr = x + (size_t)__builtin_amdgcn_readfirstlane(n) * 64;
        float acc = bv;
        #pragma unroll
        for (int k = 0; k < 64; ++k) acc = fmaf(xr[k], w[k], acc);
        hbf[n * 64 + lane] = f2bf(acc);
    }
}

// Step 1: per-block bucket histogram. Block bl owns edges
// [bl*4096, bl*4096+4096); LDS atomics only; hcnt[bucket*391 + bl].
__global__ void ema_hist_kernel(const int* ei, int* hcnt) {
    __shared__ int hist[391];
    int t = (int)threadIdx.x;
    int bl = (int)blockIdx.x;
    for (int i = t; i < 391; i += 256) hist[i] = 0;
    __syncthreads();
    int e0 = bl * 4096;
    #pragma unroll
    for (int i = 0; i < 16; ++i) {
        int e = e0 + t + i * 256;
        if (e < 1600000) {
            int dst = (e < 800000) ? ei[e + 800000] : ei[e - 800000];
            atomicAdd(&hist[dst >> 8], 1);
        }
    }
    __syncthreads();
    for (int i = t; i < 391; i += 256) hcnt[i * 391 + bl] = hist[i];
}

// Step 2a: per-bucket row: exclusive scan of 391 block counts (no base),
// and emit the row total.
__global__ void ema_bscan_row_kernel(int* hcnt, int* btot) {
    __shared__ int s[512];
    int bu = (int)blockIdx.x;
    int t = (int)threadIdx.x;
    int v = (t < 391) ? hcnt[bu * 391 + t] : 0;
    s[t] = v;
    __syncthreads();
    for (int off = 1; off < 512; off <<= 1) {
        int add = (t >= off) ? s[t - off] : 0;
        __syncthreads();
        s[t] += add;
        __syncthreads();
    }
    if (t < 391) hcnt[bu * 391 + t] = s[t] - v;
    if (t == 390) btot[bu] = s[t];
}

// Step 2b: single block: exclusive scan of bucket totals -> bbase[0..391].
// bbase[bu] equals the old rs[bu<<8]; bbase[391] = 1,600,000.
__global__ void ema_bscan_base_kernel(const int* btot, int* bbase) {
    __shared__ int s[512];
    int t = (int)threadIdx.x;
    int v = (t < 391) ? btot[t] : 0;
    s[t] = v;
    __syncthreads();
    for (int off = 1; off < 512; off <<= 1) {
        int add = (t >= off) ? s[t - off] : 0;
        __syncthreads();
        s[t] += add;
        __syncthreads();
    }
    if (t < 391) bbase[t] = s[t] - v;
    if (t == 390) bbase[391] = s[t];
}

// Step 3: scatter into stage at per-(bucket,block) bases (row scan + bbase).
// Re-reads the block's edges (L2-hot); LDS counters give within-run rank.
__global__ void ema_scatter_kernel(const int* ei, const int* hcnt,
                                   const int* bbase, unsigned int* stage) {
    __shared__ int base[391];
    __shared__ int cnt[391];
    int t = (int)threadIdx.x;
    int bl = (int)blockIdx.x;
    for (int i = t; i < 391; i += 256) {
        base[i] = hcnt[i * 391 + bl] + bbase[i];
        cnt[i] = 0;
    }
    __syncthreads();
    int e0 = bl * 4096;
    #pragma unroll
    for (int i = 0; i < 16; ++i) {
        int e = e0 + t + i * 256;
        if (e < 1600000) {
            int src = ei[e];
            int dst = (e < 800000) ? ei[e + 800000] : ei[e - 800000];
            int bu = dst >> 8;
            int slot = base[bu] + atomicAdd(&cnt[bu], 1);
            stage[slot] = ((unsigned int)(dst & 255) << 24) | (unsigned int)src;
        }
    }
}

// Step 4a: one block per bucket: count the 256 local ids over the stage
// segment (LDS atomics), block exclusive scan -> degi[] and rs[].
__global__ void ema_fillcsr_count_kernel(const int* __restrict__ bbase,
                                         const unsigned int* __restrict__ stage,
                                         int* __restrict__ degi,
                                         int* __restrict__ rs) {
    __shared__ int cnt[256];
    __shared__ int scn[256];
    int b = (int)blockIdx.x;
    int t = (int)threadIdx.x;
    cnt[t] = 0;
    __syncthreads();
    int seg_lo = bbase[b];
    int seg_hi = bbase[b + 1];
    for (int i = seg_lo + t; i < seg_hi; i += 256) {
        atomicAdd(&cnt[stage[i] >> 24], 1);
    }
    __syncthreads();
    int v = cnt[t];
    scn[t] = v;
    __syncthreads();
    for (int off = 1; off < 256; off <<= 1) {
        int add = (t >= off) ? scn[t - off] : 0;
        __syncthreads();
        scn[t] += add;
        __syncthreads();
    }
    int node = (b << 8) + t;
    if (node < 100000) {
        degi[node] = v;
        rs[node] = seg_lo + scn[t] - v;
    }
}

// Step 4b: one block per bucket; LDS per-node slots; writes PACKED csr:
// (min(deg[src]-1,32767)<<17) | src.  degi gather is L2-resident (400 KB).
__global__ void ema_fillcsr_write_kernel(const int* __restrict__ rs,
                                         const unsigned int* __restrict__ stage,
                                         const int* __restrict__ degi,
                                         int* __restrict__ csr) {
    __shared__ int rsl[256];
    __shared__ int cnt[256];
    int b = (int)blockIdx.x;
    int t = (int)threadIdx.x;
    int node_lo = b << 8;
    int node = node_lo + t;
    rsl[t] = (node < 100000) ? rs[node] : 1600000;
    cnt[t] = 0;
    __syncthreads();
    int seg_lo = rsl[0];
    int seg_hi = (node_lo + 256 < 100000) ? rs[node_lo + 256] : 1600000;
    for (int i = seg_lo + t; i < seg_hi; i += 256) {
        unsigned int v = stage[i];
        int local = (int)(v >> 24);
        int srcn = (int)(v & 0x00FFFFFFu);
        int dm1 = degi[srcn] - 1;
        if (dm1 < 0) dm1 = 0;
        if (dm1 > 32767) dm1 = 32767;
        int slot = rsl[local] + atomicAdd(&cnt[local], 1);
        csr[slot] = (dm1 << 17) | srcn;
    }
}

// Pass A: gather hbf rows; emit m0, W1, W2, W3a and pp=(r c P1, r c).
// Own-node (alpha, c) computed inline from dv (bit-identical to old coef).
__global__ void ema_passA_kernel(const int* __restrict__ degi, const int* __restrict__ rs,
                                 const int* __restrict__ csr,
                                 const unsigned short* __restrict__ hbf,
                                 unsigned short* __restrict__ m0, unsigned short* __restrict__ W1,
                                 unsigned short* __restrict__ W2, unsigned short* __restrict__ W3a,
                                 float2* __restrict__ pp) {
    int wid = (int)((blockIdx.x * 256 + threadIdx.x) >> 6);
    int c = (int)(threadIdx.x & 63);
    if (wid >= 100000) return;
    int dv = __builtin_amdgcn_readfirstlane(degi[wid]);
    int base = wid * 64 + c;
    float hv = bf2f(hbf[base]);
    if (dv == 0) {
        m0[base] = 0;
        W1[base] = 0;
        W2[base] = 0;
        W3a[base] = f2bf(hv);   // y = h for isolated nodes
        if (c == 0) pp[wid] = make_float2(0.0f, 0.0f);
        return;
    }
    int j = __builtin_amdgcn_readfirstlane(rs[wid]);
    int end = j + dv;
    float av = (dv > 1) ? 0.5f : 1.0f;
    float cv = (dv > 1) ? 0.5f / ((float)dv - 1.0f + 1e-9f) : 0.0f;
    float fv = av * hv;
    float sm = 0.0f, sS = 0.0f, sQ = 0.0f, p1 = 0.0f, p2 = 0.0f;
    for (; j + 4 <= end; j += 4) {
        unsigned int w0 = (unsigned int)csr[j];
        unsigned int w1 = (unsigned int)csr[j + 1];
        unsigned int w2 = (unsigned int)csr[j + 2];
        unsigned int w3 = (unsigned int)csr[j + 3];
        int a0 = (int)(w0 & 0x1FFFFu), d0 = (int)(w0 >> 17);
        int a1 = (int)(w1 & 0x1FFFFu), d1 = (int)(w1 >> 17);
        int a2 = (int)(w2 & 0x1FFFFu), d2 = (int)(w2 >> 17);
        int a3 = (int)(w3 & 0x1FFFFu), d3 = (int)(w3 >> 17);
        float h0 = bf2f(hbf[a0 * 64 + c]);
        float h1 = bf2f(hbf[a1 * 64 + c]);
        float h2 = bf2f(hbf[a2 * 64 + c]);
        float h3 = bf2f(hbf[a3 * 64 + c]);
        float c0 = edge_c(d0), c1 = edge_c(d1), c2 = edge_c(d2), c3 = edge_c(d3);
        float al0 = d0 ? 0.5f : 1.0f;
        float al1 = d1 ? 0.5f : 1.0f;
        float al2 = d2 ? 0.5f : 1.0f;
        float al3 = d3 ? 0.5f : 1.0f;
        sm += (h0 + h1) + (h2 + h3);
        sS += al0 * h0 + al1 * h1 + al2 * h2 + al3 * h3;
        sQ += c0 * h0 + c1 * h1 + c2 * h2 + c3 * h3;
        p1 += (c0 + c1) + (c2 + c3);
        p2 += c0 * c0 + c1 * c1 + c2 * c2 + c3 * c3;
    }
    for (; j < end; ++j) {
        unsigned int w0 = (unsigned int)csr[j];
        int a = (int)(w0 & 0x1FFFFu), d0 = (int)(w0 >> 17);
        float ha = bf2f(hbf[a * 64 + c]);
        float ca = edge_c(d0);
        float ala = d0 ? 0.5f : 1.0f;
        sm += ha;
        sS += ala * ha;
        sQ += ca * ha;
        p1 += ca;
        p2 += ca * ca;
    }
    float r = 0.5f / ((float)dv + 1e-9f);
    float w1o = sS - hv * p1;
    float w2o = sS - fv * p1 - cv * p1 * sm + cv * sQ;
    float w3o = 0.5f * hv + r * (sS - fv * p1 + 0.5f * cv * sQ - cv * hv * p2);
    m0[base] = f2bf(sm);
    W1[base] = f2bf(w1o);
    W2[base] = f2bf(w2o);
    W3a[base] = f2bf(w3o);
    if (c == 0) pp[wid] = make_float2(r * cv * p1, r * cv);
}

// Pass B: gather m0 rows; m1 = W1 + sum c_a m0[a] (in place over W1);
// W4 = W3a - pp.x*m1 + pp.y*U, U = sum c_a^2 m0[a] (in place over W3a).
__global__ void ema_passB_kernel(const int* __restrict__ degi, const int* __restrict__ rs,
                                 const int* __restrict__ csr,
                                 const unsigned short* __restrict__ m0,
                                 unsigned short* __restrict__ W1m1, unsigned short* __restrict__ W3W4,
                                 const float2* __restrict__ pp) {
    int wid = (int)((blockIdx.x * 256 + threadIdx.x) >> 6);
    int c = (int)(threadIdx.x & 63);
    if (wid >= 100000) return;
    int dv = __builtin_amdgcn_readfirstlane(degi[wid]);
    if (dv == 0) return;   // slots already hold m1=0, W4=h from pass A
    int base = wid * 64 + c;
    int j = __builtin_amdgcn_readfirstlane(rs[wid]);
    int end = j + dv;
    float t1 = 0.0f, t2 = 0.0f;
    for (; j + 4 <= end; j += 4) {
        unsigned int w0 = (unsigned int)csr[j];
        unsigned int w1 = (unsigned int)csr[j + 1];
        unsigned int w2 = (unsigned int)csr[j + 2];
        unsigned int w3 = (unsigned int)csr[j + 3];
        int a0 = (int)(w0 & 0x1FFFFu), d0 = (int)(w0 >> 17);
        int a1 = (int)(w1 & 0x1FFFFu), d1 = (int)(w1 >> 17);
        int a2 = (int)(w2 & 0x1FFFFu), d2 = (int)(w2 >> 17);
        int a3 = (int)(w3 & 0x1FFFFu), d3 = (int)(w3 >> 17);
        float m0v = bf2f(m0[a0 * 64 + c]);
        float m1v = bf2f(m0[a1 * 64 + c]);
        float m2v = bf2f(m0[a2 * 64 + c]);
        float m3v = bf2f(m0[a3 * 64 + c]);
        float c0 = edge_c(d0), c1 = edge_c(d1), c2 = edge_c(d2), c3 = edge_c(d3);
        t1 += c0 * m0v + c1 * m1v + c2 * m2v + c3 * m3v;
        t2 += c0 * c0 * m0v + c1 * c1 * m1v + c2 * c2 * m2v + c3 * c3 * m3v;
    }
    for (; j < end; ++j) {
        unsigned int w0 = (unsigned int)csr[j];
        int a = (int)(w0 & 0x1FFFFu), d0 = (int)(w0 >> 17);
        float ca = edge_c(d0);
        float mv = bf2f(m0[a * 64 + c]);
        t1 += ca * mv;
        t2 += ca * ca * mv;
    }
    float2 ppv = pp[wid];
    float m1 = bf2f(W1m1[base]) + t1;
    float w4 = bf2f(W3W4[base]) - ppv.x * m1 + ppv.y * t2;
    W1m1[base] = f2bf(m1);
    W3W4[base] = f2bf(w4);
}

// Pass C: gather m1 rows; m2 = W2 + sum c_a m1[a] (in place over W2).
__global__ void ema_passC_kernel(const int* __restrict__ degi, const int* __restrict__ rs,
                                 const int* __restrict__ csr,
                                 const unsigned short* __restrict__ m1,
                                 unsigned short* __restrict__ W2m2) {
    int wid = (int)((blockIdx.x * 256 + threadIdx.x) >> 6);
    int c = (int)(threadIdx.x & 63);
    if (wid >= 100000) return;
    int dv = __builtin_amdgcn_readfirstlane(degi[wid]);
    if (dv == 0) return;   // slot already holds m2=0
    int base = wid * 64 + c;
    int j = __builtin_amdgcn_readfirstlane(rs[wid]);
    int end = j + dv;
    float t = 0.0f;
    for (; j + 4 <= end; j += 4) {
        unsigned int w0 = (unsigned int)csr[j];
        unsigned int w1 = (unsigned int)csr[j + 1];
        unsigned int w2 = (unsigned int)csr[j + 2];
        unsigned int w3 = (unsigned int)csr[j + 3];
        int a0 = (int)(w0 & 0x1FFFFu), d0 = (int)(w0 >> 17);
        int a1 = (int)(w1 & 0x1FFFFu), d1 = (int)(w1 >> 17);
        int a2 = (int)(w2 & 0x1FFFFu), d2 = (int)(w2 >> 17);
        int a3 = (int)(w3 & 0x1FFFFu), d3 = (int)(w3 >> 17);
        float m0v = bf2f(m1[a0 * 64 + c]);
        float m1v = bf2f(m1[a1 * 64 + c]);
        float m2v = bf2f(m1[a2 * 64 + c]);
        float m3v = bf2f(m1[a3 * 64 + c]);
        float c0 = edge_c(d0), c1 = edge_c(d1), c2 = edge_c(d2), c3 = edge_c(d3);
        t += c0 * m0v + c1 * m1v + c2 * m2v + c3 * m3v;
    }
    for (; j < end; ++j) {
        unsigned int w0 = (unsigned int)csr[j];
        int a = (int)(w0 & 0x1FFFFu), d0 = (int)(w0 >> 17);
        t += edge_c(d0) * bf2f(m1[a * 64 + c]);
    }
    float m2v = bf2f(W2m2[base]) + t;
    W2m2[base] = f2bf(m2v);
}

// Pass D (identifier kernel): gather m2 rows; y = W4 + r*sum c_a m2[a];
// out = x + relu(y). Overwrites all of d_out (m0 region is dead).
__global__ void GraphEMALayer_18133351924067_kernel(
    const int* __restrict__ degi, const int* __restrict__ rs,
    const int* __restrict__ csr,
    const unsigned short* __restrict__ m2, const unsigned short* __restrict__ W4,
    const float* __restrict__ x, float* __restrict__ out) {
    int wid = (int)((blockIdx.x * 256 + threadIdx.x) >> 6);
    int c = (int)(threadIdx.x & 63);
    if (wid >= 100000) return;
    int dv = __builtin_amdgcn_readfirstlane(degi[wid]);
    int base = wid * 64 + c;
    float xv = x[base];
    float y = bf2f(W4[base]);
    if (dv > 0) {
        int j = __builtin_amdgcn_readfirstlane(rs[wid]);
        int end = j + dv;
        float t = 0.0f;
        for (; j + 4 <= end; j += 4) {
            unsigned int w0 = (unsigned int)csr[j];
            unsigned int w1 = (unsigned int)csr[j + 1];
            unsigned int w2 = (unsigned int)csr[j + 2];
            unsigned int w3 = (unsigned int)csr[j + 3];
            int a0 = (int)(w0 & 0x1FFFFu), d0 = (int)(w0 >> 17);
            int a1 = (int)(w1 & 0x1FFFFu), d1 = (int)(w1 >> 17);
            int a2 = (int)(w2 & 0x1FFFFu), d2 = (int)(w2 >> 17);
            int a3 = (int)(w3 & 0x1FFFFu), d3 = (int)(w3 >> 17);
            float m0v = bf2f(m2[a0 * 64 + c]);
            float m1v = bf2f(m2[a1 * 64 + c]);
            float m2v = bf2f(m2[a2 * 64 + c]);
            float m3v = bf2f(m2[a3 * 64 + c]);
            float c0 = edge_c(d0), c1 = edge_c(d1), c2 = edge_c(d2), c3 = edge_c(d3);
            t += c0 * m0v + c1 * m1v + c2 * m2v + c3 * m3v;
        }
        for (; j < end; ++j) {
            unsigned int w0 = (unsigned int)csr[j];
            int a = (int)(w0 & 0x1FFFFu), d0 = (int)(w0 >> 17);
            t += edge_c(d0) * bf2f(m2[a * 64 + c]);
        }
        float r = 0.5f / ((float)dv + 1e-9f);
        y += r * t;
    }
    if (y < 0.0f) y = 0.0f;
    out[base] = xv + y;
}

extern "C" void kernel_launch(void* const* d_in, const int* in_sizes, int n_in,
                              void* d_out, int out_size, void* d_ws, size_t ws_size,
                              hipStream_t stream) {
    (void)in_sizes; (void)n_in; (void)out_size; (void)ws_size;

    const float* x    = (const float*)d_in[0];
    const int*   ei   = (const int*)d_in[1];
    const float* W    = (const float*)d_in[2];
    const float* bias = (const float*)d_in[3];
    float* out = (float*)d_out;
    unsigned short* m0 = (unsigned short*)d_out;   // first 12.8 MB, dead before D

    char* ws = (char*)d_ws;
    unsigned short* hbf  = (unsigned short*)(ws);             // 12,800,000 B
    unsigned short* W1m1 = (unsigned short*)(ws + 12800000);  // 12,800,000 B
    unsigned short* W2m2 = (unsigned short*)(ws + 25600000);  // 12,800,000 B
    unsigned short* W3W4 = (unsigned short*)(ws + 38400000);  // 12,800,000 B
    int* degi = (int*)(ws + 51200000);                        //    400,000 B
    int* rs   = (int*)(ws + 51600000);                        //    400,000 B
    float2* pp   = (float2*)(ws + 52800000);                  //    800,000 B
    int* csr  = (int*)(ws + 53600000);                        //  6,400,000 B
    int* bbase = (int*)(ws + 60000000);                       //      1,568 B
    int* btot  = (int*)(ws + 60002048);                       //      1,564 B

    // CSR-build scratch, both dead before pass A writes them:
    unsigned int* stage = (unsigned int*)(ws + 12800000);     // aliases W1m1, 6.4 MB
    int* hcnt = (int*)(ws + 25600000);                        // aliases W2m2, 611,524 B

    int eb = (100000 * 64 + 255) / 256;   // 25000 blocks: wave-per-node grids
    int nb = (100000 + 255) / 256;        //   391 blocks: per-bucket grids
    int pb = (1600000 + 4095) / 4096;     //   391 blocks: partition grids
    int gb = (100000 + 31) / 32;          //  3125 blocks: gemm (32 nodes/block)

    ema_gemm_kernel<<<gb, 256, 0, stream>>>(x, W, bias, hbf);

    ema_hist_kernel<<<pb, 256, 0, stream>>>(ei, hcnt);
    ema_bscan_row_kernel<<<391, 512, 0, stream>>>(hcnt, btot);
    ema_bscan_base_kernel<<<1, 512, 0, stream>>>(btot, bbase);
    ema_scatter_kernel<<<pb, 256, 0, stream>>>(ei, hcnt, bbase, stage);
    ema_fillcsr_count_kernel<<<nb, 256, 0, stream>>>(bbase, stage, degi, rs);
    ema_fillcsr_write_kernel<<<nb, 256, 0, stream>>>(rs, stage, degi, csr);

    ema_passA_kernel<<<eb, 256, 0, stream>>>(degi, rs, csr, hbf,
                                             m0, W1m1, W2m2, W3W4, pp);
    ema_passB_kernel<<<eb, 256, 0, stream>>>(degi, rs, csr, m0,
                                             W1m1, W3W4, pp);
    ema_passC_kernel<<<eb, 256, 0, stream>>>(degi, rs, csr, W1m1, W2m2);
    GraphEMALayer_18133351924067_kernel<<<eb, 256, 0, stream>>>(
        degi, rs, csr, W2m2, W3W4, x, out);
}